// Round 7
// baseline (1243.230 us; speedup 1.0000x reference)
//
#include <hip/hip_runtime.h>

#define NN 500
#define BB 8
#define FIN 8
#define TT 12
#define HH 16
#define EE 8000
#define HG 4000          // N*HID
#define IG 8000          // N*H3
#define G3 12000         // 3*HG
#define MM 96            // T*B

typedef __attribute__((ext_vector_type(8))) _Float16 half8;
typedef __attribute__((ext_vector_type(4))) _Float16 half4v;
typedef __attribute__((ext_vector_type(4))) float f32x4;

// ---------------------------------------------------------------- graph prep
__global__ __launch_bounds__(512) void k_prep(const int* __restrict__ src,
                                              const int* __restrict__ dst,
                                              float* __restrict__ n_out,
                                              float* __restrict__ n_in,
                                              int* __restrict__ row_ptr,
                                              int* __restrict__ edge_src) {
  __shared__ int s_dout[NN];
  __shared__ int s_din[NN];
  __shared__ int s_off[NN + 1];
  int tid = threadIdx.x;
  for (int i = tid; i < NN; i += 512) { s_dout[i] = 0; s_din[i] = 0; }
  __syncthreads();
  for (int e = tid; e < EE; e += 512) {
    atomicAdd(&s_dout[src[e]], 1);
    atomicAdd(&s_din[dst[e]], 1);
  }
  __syncthreads();
  if (tid == 0) {
    int acc = 0;
    for (int n = 0; n < NN; ++n) { s_off[n] = acc; acc += s_din[n]; }
    s_off[NN] = acc;
  }
  __syncthreads();
  for (int i = tid; i < NN; i += 512) {
    int dv = s_dout[i]; if (dv < 1) dv = 1;
    int iv = s_din[i];  if (iv < 1) iv = 1;
    n_out[i] = rsqrtf((float)dv);
    n_in[i]  = rsqrtf((float)iv);
    row_ptr[i] = s_off[i];
  }
  if (tid == 0) row_ptr[NN] = s_off[NN];
  __syncthreads();
  for (int e = tid; e < EE; e += 512) {
    int d = dst[e];
    int pos = atomicAdd(&s_off[d], 1);
    edge_src[pos] = src[e];
  }
}

// ------------------------------------------------- transpose inputs to [t][n][b][f]
__global__ __launch_bounds__(256) void k_transpose(const float* __restrict__ in,
                                                   float* __restrict__ out) {
  int idx = blockIdx.x * 256 + threadIdx.x;   // over T*N*B*FIN
  if (idx >= TT * NN * BB * FIN) return;
  int f = idx % FIN;
  int b = (idx / FIN) % BB;
  int n = (idx / (FIN * BB)) % NN;
  int t = idx / (FIN * BB * NN);
  out[idx] = in[((n * BB + b) * FIN + f) * TT + t];
}

// ---------------------------------------------------------------- GCN layer
template <int FI, int FO, bool RELU, typename OT, bool OUT_SEQ>
__global__ __launch_bounds__(128) void k_gcn(const float* __restrict__ x,
                                             const float* __restrict__ W,
                                             const float* __restrict__ bias,
                                             const float* __restrict__ n_out,
                                             const float* __restrict__ n_in,
                                             const int* __restrict__ row_ptr,
                                             const int* __restrict__ edge_src,
                                             OT* __restrict__ y) {
  int bid = blockIdx.x;             // t*NN + n
  int t = bid / NN, n = bid % NN;
  __shared__ float sW[FI * FO];
  __shared__ float sB[FO];
  __shared__ float sAgg[BB * FI];
  int tid = threadIdx.x;
  for (int i = tid; i < FI * FO; i += 128) sW[i] = W[i];
  if (tid < FO) sB[tid] = bias[tid];
  int r0 = row_ptr[n], r1 = row_ptr[n + 1];
  if (tid < BB * FI) {
    int b = tid / FI, fi = tid % FI;
    float acc = 0.f;
    for (int p = r0; p < r1; ++p) {
      int s = edge_src[p];
      acc += x[((t * NN + s) * BB + b) * FI + fi] * n_out[s];
    }
    sAgg[tid] = acc * n_in[n];
  }
  __syncthreads();
  if (tid < BB * FO) {
    int b = tid / FO, fo = tid % FO;
    float v = sB[fo];
#pragma unroll
    for (int fi = 0; fi < FI; ++fi) v += sAgg[b * FI + fi] * sW[fi * FO + fo];
    if (RELU) v = fmaxf(v, 0.f);
    int oidx = OUT_SEQ ? (((t * BB + b) * NN + n) * FO + fo)
                       : (((t * NN + n) * BB + b) * FO + fo);
    y[oidx] = (OT)v;
  }
}

// ------------------------------------------------- Whh fp32 -> fp16 (once)
__global__ __launch_bounds__(256) void k_cvt_whh(const float* __restrict__ w,
                                                 _Float16* __restrict__ wh) {
  size_t i8 = ((size_t)blockIdx.x * 256 + threadIdx.x) * 8;
  if (i8 >= (size_t)G3 * HG) return;
  float4 a = *(const float4*)(w + i8);
  float4 b = *(const float4*)(w + i8 + 4);
  half8 h;
  h[0] = (_Float16)a.x; h[1] = (_Float16)a.y; h[2] = (_Float16)a.z; h[3] = (_Float16)a.w;
  h[4] = (_Float16)b.x; h[5] = (_Float16)b.y; h[6] = (_Float16)b.z; h[7] = (_Float16)b.w;
  *(half8*)(wh + i8) = h;
}

// ------------------------------------------------------------ gi = X @ Wih^T
// fp16 MFMA single pass.  Xh: [96][8000] fp16, Wih: [12000][8000] fp32 (cvt in-kernel).
// gip: [2][96][12000] K-split partials.  grid (375, 2), block 256 (4 waves).
__global__ __launch_bounds__(256, 3) void k_gemm_gi_mfma(const _Float16* __restrict__ Xh,
                                                         const float* __restrict__ Wih,
                                                         float* __restrict__ gip) {
  __shared__ _Float16 sXh[96 * 40];   // rows padded to 40 halves (80B stride)
  __shared__ _Float16 sWh[32 * 40];
  int tid = threadIdx.x;
  int wave = tid >> 6, lane = tid & 63;
  int jb = blockIdx.x * 32;
  int kbase = blockIdx.y * 4000;       // K_s = 4000, 125 chunks of 32

  int xrow[3], xc4[3];
  const ushort4* px[3];
#pragma unroll
  for (int i = 0; i < 3; ++i) {
    int idx = i * 256 + tid;           // 768 units = 96 rows x 8 half4
    xrow[i] = idx >> 3; xc4[i] = idx & 7;
    px[i] = (const ushort4*)(Xh + (size_t)xrow[i] * IG + kbase + xc4[i] * 4);
  }
  int wrow = tid >> 3, wc4 = tid & 7;  // 256 f4 = 32 rows x 8 f4
  const float4* pw = (const float4*)(Wih + (size_t)(jb + wrow) * IG + kbase + wc4 * 4);

  int jt = wave & 1;                    // j-tile within block
  int mh = wave >> 1;                   // m-half (48 rows)
  f32x4 acc[3] = {{0.f,0.f,0.f,0.f},{0.f,0.f,0.f,0.f},{0.f,0.f,0.f,0.f}};

  ushort4 xr[3]; float4 wr;
#pragma unroll
  for (int i = 0; i < 3; ++i) xr[i] = px[i][0];
  wr = pw[0];

  int l15 = lane & 15;
  int colh = (lane >> 4) * 8;

  for (int c = 0; c < 125; ++c) {
    __syncthreads();
#pragma unroll
    for (int i = 0; i < 3; ++i)
      *(ushort4*)&sXh[xrow[i] * 40 + xc4[i] * 4] = xr[i];
    {
      half4v h;
      h[0] = (_Float16)wr.x; h[1] = (_Float16)wr.y;
      h[2] = (_Float16)wr.z; h[3] = (_Float16)wr.w;
      *(half4v*)&sWh[wrow * 40 + wc4 * 4] = h;
    }
    __syncthreads();
    if (c < 124) {
#pragma unroll
      for (int i = 0; i < 3; ++i) xr[i] = px[i][(c + 1) * 8];
      wr = pw[(c + 1) * 8];
    }
    half8 bfrag = *(const half8*)&sWh[(jt * 16 + l15) * 40 + colh];
#pragma unroll
    for (int t = 0; t < 3; ++t) {
      half8 afrag = *(const half8*)&sXh[(mh * 48 + t * 16 + l15) * 40 + colh];
      acc[t] = __builtin_amdgcn_mfma_f32_16x16x32_f16(afrag, bfrag, acc[t], 0, 0, 0);
    }
  }

  // D: col = lane&15 (j), row m = (lane>>4)*4 + reg  [validated rounds 3-6]
  float* out = gip + (size_t)blockIdx.y * (MM * G3);
  int j = jb + jt * 16 + l15;
#pragma unroll
  for (int t = 0; t < 3; ++t) {
    int mb = mh * 48 + t * 16 + (lane >> 4) * 4;
#pragma unroll
    for (int r = 0; r < 4; ++r)
      out[(size_t)(mb + r) * G3 + j] = acc[t][r];
  }
}

// ------------------------------------------------- GRU step 0 (h=0 -> gh=0)
__global__ __launch_bounds__(256) void k_gates0(const float* __restrict__ gip,
                                                const float* __restrict__ b_ih,
                                                const float* __restrict__ b_hh,
                                                float* __restrict__ h32n) {
  int idx = blockIdx.x * 256 + threadIdx.x;   // 32000 exact (125 blocks)
  int q = idx >> 3, m = idx & 7;
  const float* g0 = gip + (size_t)m * G3;                     // t=0: mg = m
  const float* g1 = gip + (size_t)MM * G3 + (size_t)m * G3;
  float ir  = b_ih[q]          + g0[q]          + g1[q];
  float iz  = b_ih[q + HG]     + g0[q + HG]     + g1[q + HG];
  float in_ = b_ih[q + 2*HG]   + g0[q + 2*HG]   + g1[q + 2*HG];
  float r = 1.f / (1.f + __expf(-(ir + b_hh[q])));
  float z = 1.f / (1.f + __expf(-(iz + b_hh[q + HG])));
  float nn = tanhf(in_ + r * b_hh[q + 2*HG]);
  h32n[idx] = (1.f - z) * nn;                 // h_old = 0
}

// ------------------------------- fused GRU step: gh partial + last-block gates
// grid (125, 4), block 256.  Block (qg, ks): 32 q-values x 3 gate rows
// {q, q+HG, q+2HG}, k-slice ks*1000..+1000.  Same inner loop as round-6 gh.
// Split-K combine: disjoint-slot agent-scope atomic publish + arrival counter;
// 4th block sums slots in fixed order (deterministic), applies gates.
__device__ __forceinline__ int swz2(int f) { return f ^ (((f >> 4) & 7) << 1); }

__global__ __launch_bounds__(256) void k_ghg(const float* __restrict__ ht,
                                             const _Float16* __restrict__ Whh_h,
                                             const float* __restrict__ gip,
                                             const float* __restrict__ b_ih,
                                             const float* __restrict__ b_hh,
                                             float* __restrict__ preS,   // [4][4000][3][8]
                                             int* __restrict__ cnt,      // [125]
                                             float* __restrict__ ht_new,
                                             float* __restrict__ hout, int t) {
  int qg = blockIdx.x;             // 0..124
  int ks = blockIdx.y;             // 0..3
  int kbase = ks * 1000;           // halves
  __shared__ float4 sH4[2000];     // [1000 k][8 m] as float4 pairs, swizzled
  __shared__ int sLast;
  int tid = threadIdx.x;
  const float4* H4 = (const float4*)ht;
#pragma unroll
  for (int l = 0; l < 8; ++l) {
    int f = l * 256 + tid;
    if (f < 2000) sH4[swz2(f)] = H4[kbase * 2 + f];
  }
  __syncthreads();
  int jl = tid >> 3;               // 0..31 -> q = qg*32 + jl
  int k8 = tid & 7;                // 0..7
  int q = qg * 32 + jl;
  const half8* W0 = (const half8*)(Whh_h + (size_t)q            * HG + kbase);
  const half8* W1 = (const half8*)(Whh_h + (size_t)(q + HG)     * HG + kbase);
  const half8* W2 = (const half8*)(Whh_h + (size_t)(q + 2 * HG) * HG + kbase);
  float acc[3][8] = {};
  for (int i = 0; i < 16; ++i) {
    int kq = i * 8 + k8;           // half8 index within slice, 0..124
    if (kq < 125) {
      half8 w0 = W0[kq], w1 = W1[kq], w2 = W2[kq];
#pragma unroll
      for (int kk = 0; kk < 8; ++kk) {
        int f = (kq * 8 + kk) * 2;
        float4 ha = sH4[swz2(f)];
        float4 hb = sH4[swz2(f + 1)];
        float hm[8] = {ha.x, ha.y, ha.z, ha.w, hb.x, hb.y, hb.z, hb.w};
        float v0 = (float)w0[kk], v1 = (float)w1[kk], v2 = (float)w2[kk];
#pragma unroll
        for (int m = 0; m < 8; ++m) {
          acc[0][m] += hm[m] * v0;
          acc[1][m] += hm[m] * v1;
          acc[2][m] += hm[m] * v2;
        }
      }
    }
  }
#pragma unroll
  for (int r = 0; r < 3; ++r)
#pragma unroll
    for (int m = 0; m < 8; ++m) {
      float v = acc[r][m];
      v += __shfl_down(v, 4, 8);
      v += __shfl_down(v, 2, 8);
      v += __shfl_down(v, 1, 8);
      acc[r][m] = v;
    }
  // publish partials to disjoint slots (agent scope: cross-XCD coherent)
  if (k8 == 0) {
    float* slot = preS + (((size_t)ks * HG + q) * 3) * 8;
#pragma unroll
    for (int g = 0; g < 3; ++g)
#pragma unroll
      for (int m = 0; m < 8; ++m)
        __hip_atomic_store(&slot[g * 8 + m], acc[g][m],
                           __ATOMIC_RELAXED, __HIP_MEMORY_SCOPE_AGENT);
  }
  __threadfence();                 // each thread's stores complete & visible
  __syncthreads();                 // all threads' stores done before arrival
  if (tid == 0) {
    int old = __hip_atomic_fetch_add(&cnt[qg], 1, __ATOMIC_ACQ_REL,
                                     __HIP_MEMORY_SCOPE_AGENT);
    sLast = (old == 3) ? 1 : 0;
  }
  __syncthreads();
  if (!sLast) return;
  __threadfence();                 // acquire side
  {
    int ql = tid >> 3, m = tid & 7;      // 256 = 32 q x 8 m exactly
    int qq = qg * 32 + ql;
    float hr = b_hh[qq], hz = b_hh[qq + HG], hn = b_hh[qq + 2 * HG];
#pragma unroll
    for (int s = 0; s < 4; ++s) {        // fixed order -> deterministic
      const float* sl = preS + (((size_t)s * HG + qq) * 3) * 8;
      hr += __hip_atomic_load(&sl[0 * 8 + m], __ATOMIC_RELAXED, __HIP_MEMORY_SCOPE_AGENT);
      hz += __hip_atomic_load(&sl[1 * 8 + m], __ATOMIC_RELAXED, __HIP_MEMORY_SCOPE_AGENT);
      hn += __hip_atomic_load(&sl[2 * 8 + m], __ATOMIC_RELAXED, __HIP_MEMORY_SCOPE_AGENT);
    }
    int mg = t * BB + m;
    const float* g0 = gip + (size_t)mg * G3;
    const float* g1 = gip + (size_t)MM * G3 + (size_t)mg * G3;
    float ir  = b_ih[qq]          + g0[qq]          + g1[qq];
    float iz  = b_ih[qq + HG]     + g0[qq + HG]     + g1[qq + HG];
    float in_ = b_ih[qq + 2*HG]   + g0[qq + 2*HG]   + g1[qq + 2*HG];
    float r = 1.f / (1.f + __expf(-(ir + hr)));
    float z = 1.f / (1.f + __expf(-(iz + hz)));
    float nn = tanhf(in_ + r * hn);
    float ho = ht[qq * BB + m];
    float h = (1.f - z) * nn + z * ho;
    ht_new[qq * BB + m] = h;
    if (hout) hout[m * HG + qq] = h;
  }
  if (tid == 0)                    // self-reset for next step's reuse
    __hip_atomic_store(&cnt[qg], 0, __ATOMIC_RELAXED, __HIP_MEMORY_SCOPE_AGENT);
}

// ---------------------------------------------------------------- launcher
extern "C" void kernel_launch(void* const* d_in, const int* in_sizes, int n_in,
                              void* d_out, int out_size, void* d_ws, size_t ws_size,
                              hipStream_t stream) {
  const float* x_in = (const float*)d_in[0];
  const int*   src  = (const int*)d_in[1];
  const int*   dst  = (const int*)d_in[2];
  const float* W1   = (const float*)d_in[3];
  const float* b1   = (const float*)d_in[4];
  const float* W2   = (const float*)d_in[5];
  const float* b2   = (const float*)d_in[6];
  const float* W3   = (const float*)d_in[7];
  const float* b3   = (const float*)d_in[8];
  const float* Wih  = (const float*)d_in[9];
  const float* Whh  = (const float*)d_in[10];
  const float* bih  = (const float*)d_in[11];
  const float* bhh  = (const float*)d_in[12];
  float* out = (float*)d_out;

  float* W = (float*)d_ws;
  size_t off = 0;
  float* n_out = W + off; off += 512;
  float* n_in_ = W + off; off += 512;
  float* x0    = W + off; off += (size_t)TT * NN * BB * FIN;   // 384000
  float* xa    = W + off; off += (size_t)TT * NN * BB * HH;    // 768000
  float* xb    = W + off; off += (size_t)TT * NN * BB * HH;    // 768000
  _Float16* xseq = (_Float16*)(W + off); off += (size_t)MM * IG / 2;
  float* gip   = W + off; off += (size_t)2 * MM * G3;          // 2304000
  float* preS  = W + off; off += (size_t)4 * HG * 3 * 8;       // 384000
  float* ht0   = W + off; off += (size_t)HG * BB;
  float* ht1   = W + off; off += (size_t)HG * BB;
  int* row_ptr  = (int*)(W + off); off += 512;
  int* edge_src = (int*)(W + off); off += 8000;
  int* cnt      = (int*)(W + off); off += 128;
  off = (off + 3) & ~(size_t)3;                                // 16B align
  _Float16* whh_h = (_Float16*)(W + off); off += (size_t)G3 * HG / 2;  // 96 MB
  (void)ws_size; (void)in_sizes; (void)n_in; (void)out_size;

  hipMemsetAsync(cnt, 0, 128 * sizeof(int), stream);
  k_cvt_whh<<<((size_t)G3 * HG / 8 + 255) / 256, 256, 0, stream>>>(Whh, whh_h);
  k_prep<<<1, 512, 0, stream>>>(src, dst, n_out, n_in_, row_ptr, edge_src);
  k_transpose<<<(TT * NN * BB * FIN + 255) / 256, 256, 0, stream>>>(x_in, x0);
  k_gcn<FIN, HH, true, float, false><<<TT * NN, 128, 0, stream>>>(x0, W1, b1, n_out, n_in_, row_ptr, edge_src, xa);
  k_gcn<HH, HH, true, float, false><<<TT * NN, 128, 0, stream>>>(xa, W2, b2, n_out, n_in_, row_ptr, edge_src, xb);
  k_gcn<HH, HH, false, _Float16, true><<<TT * NN, 128, 0, stream>>>(xb, W3, b3, n_out, n_in_, row_ptr, edge_src, xseq);
  k_gemm_gi_mfma<<<dim3(375, 2), 256, 0, stream>>>(xseq, Wih, gip);

  // t = 0: h_old = 0 -> gh = 0, skip the W_hh stream entirely
  k_gates0<<<BB * HG / 256, 256, 0, stream>>>(gip, bih, bhh, ht0);

  float* hcur = ht0;
  float* hnxt = ht1;
  for (int t = 1; t < TT; ++t) {
    k_ghg<<<dim3(125, 4), 256, 0, stream>>>(hcur, whh_h, gip, bih, bhh,
                                            preS, cnt, hnxt,
                                            (t == TT - 1) ? out : nullptr, t);
    float* tmp = hcur; hcur = hnxt; hnxt = tmp;
  }
}

// Round 8
// 535.170 us; speedup vs baseline: 2.3231x; 2.3231x over previous
//
#include <hip/hip_runtime.h>

#define NN 500
#define BB 8
#define FIN 8
#define TT 12
#define HH 16
#define EE 8000
#define HG 4000          // N*HID
#define IG 8000          // N*H3
#define G3 12000         // 3*HG
#define MM 96            // T*B

typedef __attribute__((ext_vector_type(8))) _Float16 half8;
typedef __attribute__((ext_vector_type(4))) _Float16 half4v;
typedef __attribute__((ext_vector_type(4))) float f32x4;

// ---------------------------------------------------------------- graph prep
__global__ __launch_bounds__(512) void k_prep(const int* __restrict__ src,
                                              const int* __restrict__ dst,
                                              float* __restrict__ n_out,
                                              float* __restrict__ n_in,
                                              int* __restrict__ row_ptr,
                                              int* __restrict__ edge_src) {
  __shared__ int s_dout[NN];
  __shared__ int s_din[NN];
  __shared__ int s_off[NN + 1];
  int tid = threadIdx.x;
  for (int i = tid; i < NN; i += 512) { s_dout[i] = 0; s_din[i] = 0; }
  __syncthreads();
  for (int e = tid; e < EE; e += 512) {
    atomicAdd(&s_dout[src[e]], 1);
    atomicAdd(&s_din[dst[e]], 1);
  }
  __syncthreads();
  if (tid == 0) {
    int acc = 0;
    for (int n = 0; n < NN; ++n) { s_off[n] = acc; acc += s_din[n]; }
    s_off[NN] = acc;
  }
  __syncthreads();
  for (int i = tid; i < NN; i += 512) {
    int dv = s_dout[i]; if (dv < 1) dv = 1;
    int iv = s_din[i];  if (iv < 1) iv = 1;
    n_out[i] = rsqrtf((float)dv);
    n_in[i]  = rsqrtf((float)iv);
    row_ptr[i] = s_off[i];
  }
  if (tid == 0) row_ptr[NN] = s_off[NN];
  __syncthreads();
  for (int e = tid; e < EE; e += 512) {
    int d = dst[e];
    int pos = atomicAdd(&s_off[d], 1);
    edge_src[pos] = src[e];
  }
}

// ------------------------------------------------- transpose inputs to [t][n][b][f]
__global__ __launch_bounds__(256) void k_transpose(const float* __restrict__ in,
                                                   float* __restrict__ out) {
  int idx = blockIdx.x * 256 + threadIdx.x;   // over T*N*B*FIN
  if (idx >= TT * NN * BB * FIN) return;
  int f = idx % FIN;
  int b = (idx / FIN) % BB;
  int n = (idx / (FIN * BB)) % NN;
  int t = idx / (FIN * BB * NN);
  out[idx] = in[((n * BB + b) * FIN + f) * TT + t];
}

// ---------------------------------------------------------------- GCN layer
template <int FI, int FO, bool RELU, typename OT, bool OUT_SEQ>
__global__ __launch_bounds__(128) void k_gcn(const float* __restrict__ x,
                                             const float* __restrict__ W,
                                             const float* __restrict__ bias,
                                             const float* __restrict__ n_out,
                                             const float* __restrict__ n_in,
                                             const int* __restrict__ row_ptr,
                                             const int* __restrict__ edge_src,
                                             OT* __restrict__ y) {
  int bid = blockIdx.x;             // t*NN + n
  int t = bid / NN, n = bid % NN;
  __shared__ float sW[FI * FO];
  __shared__ float sB[FO];
  __shared__ float sAgg[BB * FI];
  int tid = threadIdx.x;
  for (int i = tid; i < FI * FO; i += 128) sW[i] = W[i];
  if (tid < FO) sB[tid] = bias[tid];
  int r0 = row_ptr[n], r1 = row_ptr[n + 1];
  if (tid < BB * FI) {
    int b = tid / FI, fi = tid % FI;
    float acc = 0.f;
    for (int p = r0; p < r1; ++p) {
      int s = edge_src[p];
      acc += x[((t * NN + s) * BB + b) * FI + fi] * n_out[s];
    }
    sAgg[tid] = acc * n_in[n];
  }
  __syncthreads();
  if (tid < BB * FO) {
    int b = tid / FO, fo = tid % FO;
    float v = sB[fo];
#pragma unroll
    for (int fi = 0; fi < FI; ++fi) v += sAgg[b * FI + fi] * sW[fi * FO + fo];
    if (RELU) v = fmaxf(v, 0.f);
    int oidx = OUT_SEQ ? (((t * BB + b) * NN + n) * FO + fo)
                       : (((t * NN + n) * BB + b) * FO + fo);
    y[oidx] = (OT)v;
  }
}

// ------------------------------------------------- Whh fp32 -> fp16 (once)
__global__ __launch_bounds__(256) void k_cvt_whh(const float* __restrict__ w,
                                                 _Float16* __restrict__ wh) {
  size_t i8 = ((size_t)blockIdx.x * 256 + threadIdx.x) * 8;
  if (i8 >= (size_t)G3 * HG) return;
  float4 a = *(const float4*)(w + i8);
  float4 b = *(const float4*)(w + i8 + 4);
  half8 h;
  h[0] = (_Float16)a.x; h[1] = (_Float16)a.y; h[2] = (_Float16)a.z; h[3] = (_Float16)a.w;
  h[4] = (_Float16)b.x; h[5] = (_Float16)b.y; h[6] = (_Float16)b.z; h[7] = (_Float16)b.w;
  *(half8*)(wh + i8) = h;
}

// ------------------------------------------------------------ gi = X @ Wih^T
// fp16 MFMA single pass.  Xh: [96][8000] fp16, Wih: [12000][8000] fp32 (cvt in-kernel).
// gip: [2][96][12000] K-split partials.  grid (375, 2), block 256 (4 waves).
__global__ __launch_bounds__(256, 3) void k_gemm_gi_mfma(const _Float16* __restrict__ Xh,
                                                         const float* __restrict__ Wih,
                                                         float* __restrict__ gip) {
  __shared__ _Float16 sXh[96 * 40];   // rows padded to 40 halves (80B stride)
  __shared__ _Float16 sWh[32 * 40];
  int tid = threadIdx.x;
  int wave = tid >> 6, lane = tid & 63;
  int jb = blockIdx.x * 32;
  int kbase = blockIdx.y * 4000;       // K_s = 4000, 125 chunks of 32

  int xrow[3], xc4[3];
  const ushort4* px[3];
#pragma unroll
  for (int i = 0; i < 3; ++i) {
    int idx = i * 256 + tid;           // 768 units = 96 rows x 8 half4
    xrow[i] = idx >> 3; xc4[i] = idx & 7;
    px[i] = (const ushort4*)(Xh + (size_t)xrow[i] * IG + kbase + xc4[i] * 4);
  }
  int wrow = tid >> 3, wc4 = tid & 7;  // 256 f4 = 32 rows x 8 f4
  const float4* pw = (const float4*)(Wih + (size_t)(jb + wrow) * IG + kbase + wc4 * 4);

  int jt = wave & 1;                    // j-tile within block
  int mh = wave >> 1;                   // m-half (48 rows)
  f32x4 acc[3] = {{0.f,0.f,0.f,0.f},{0.f,0.f,0.f,0.f},{0.f,0.f,0.f,0.f}};

  ushort4 xr[3]; float4 wr;
#pragma unroll
  for (int i = 0; i < 3; ++i) xr[i] = px[i][0];
  wr = pw[0];

  int l15 = lane & 15;
  int colh = (lane >> 4) * 8;

  for (int c = 0; c < 125; ++c) {
    __syncthreads();
#pragma unroll
    for (int i = 0; i < 3; ++i)
      *(ushort4*)&sXh[xrow[i] * 40 + xc4[i] * 4] = xr[i];
    {
      half4v h;
      h[0] = (_Float16)wr.x; h[1] = (_Float16)wr.y;
      h[2] = (_Float16)wr.z; h[3] = (_Float16)wr.w;
      *(half4v*)&sWh[wrow * 40 + wc4 * 4] = h;
    }
    __syncthreads();
    if (c < 124) {
#pragma unroll
      for (int i = 0; i < 3; ++i) xr[i] = px[i][(c + 1) * 8];
      wr = pw[(c + 1) * 8];
    }
    half8 bfrag = *(const half8*)&sWh[(jt * 16 + l15) * 40 + colh];
#pragma unroll
    for (int t = 0; t < 3; ++t) {
      half8 afrag = *(const half8*)&sXh[(mh * 48 + t * 16 + l15) * 40 + colh];
      acc[t] = __builtin_amdgcn_mfma_f32_16x16x32_f16(afrag, bfrag, acc[t], 0, 0, 0);
    }
  }

  // D: col = lane&15 (j), row m = (lane>>4)*4 + reg  [validated rounds 3-7]
  float* out = gip + (size_t)blockIdx.y * (MM * G3);
  int j = jb + jt * 16 + l15;
#pragma unroll
  for (int t = 0; t < 3; ++t) {
    int mb = mh * 48 + t * 16 + (lane >> 4) * 4;
#pragma unroll
    for (int r = 0; r < 4; ++r)
      out[(size_t)(mb + r) * G3 + j] = acc[t][r];
  }
}

// ------------------------------------------------- GRU step 0 (h=0 -> gh=0)
__global__ __launch_bounds__(256) void k_gates0(const float* __restrict__ gip,
                                                const float* __restrict__ b_ih,
                                                const float* __restrict__ b_hh,
                                                float* __restrict__ h32n) {
  int idx = blockIdx.x * 256 + threadIdx.x;   // 32000 exact (125 blocks)
  int q = idx >> 3, m = idx & 7;
  const float* g0 = gip + (size_t)m * G3;                     // t=0: mg = m
  const float* g1 = gip + (size_t)MM * G3 + (size_t)m * G3;
  float ir  = b_ih[q]          + g0[q]          + g1[q];
  float iz  = b_ih[q + HG]     + g0[q + HG]     + g1[q + HG];
  float in_ = b_ih[q + 2*HG]   + g0[q + 2*HG]   + g1[q + 2*HG];
  float r = 1.f / (1.f + __expf(-(ir + b_hh[q])));
  float z = 1.f / (1.f + __expf(-(iz + b_hh[q + HG])));
  float nn = tanhf(in_ + r * b_hh[q + 2*HG]);
  h32n[idx] = (1.f - z) * nn;                 // h_old = 0
}

// --------------------------- fused GRU step: full-K gh + in-block gates
// grid 500, block 256.  Block owns 8 q-values x full K=4000 x 3 gate rows
// {q, q+HG, q+2HG}; h staged fp16 in LDS (64 KB, XOR-swizzled).
// 32 lanes per q; width-32 shuffle reduce; 64-thread gate epilogue.
// No cross-block sync (the round-7 failure mode is structurally absent).
__global__ __launch_bounds__(256) void k_ghf(const float* __restrict__ ht,
                                             const _Float16* __restrict__ wh,
                                             const float* __restrict__ gip,
                                             const float* __restrict__ b_ih,
                                             const float* __restrict__ b_hh,
                                             float* __restrict__ ht_new,
                                             float* __restrict__ hout, int t) {
  __shared__ half8 sH[4000];          // 64 KB; unit u = k, swizzled u^((u>>3)&7)
  __shared__ float sAcc[8][3][8];
  int tid = threadIdx.x;
  const float4* H4 = (const float4*)ht;
  for (int l = 0; l < 16; ++l) {      // stage h: fp32 -> fp16
    int u = l * 256 + tid;
    if (u < HG) {
      float4 a = H4[u * 2], b = H4[u * 2 + 1];
      half8 h;
      h[0] = (_Float16)a.x; h[1] = (_Float16)a.y; h[2] = (_Float16)a.z; h[3] = (_Float16)a.w;
      h[4] = (_Float16)b.x; h[5] = (_Float16)b.y; h[6] = (_Float16)b.z; h[7] = (_Float16)b.w;
      sH[u ^ ((u >> 3) & 7)] = h;
    }
  }
  __syncthreads();

  int q_l = tid >> 5, ks = tid & 31;
  int q = blockIdx.x * 8 + q_l;
  const half8* __restrict__ W0 = (const half8*)(wh + (size_t)q            * HG);
  const half8* __restrict__ W1 = (const half8*)(wh + (size_t)(q + HG)     * HG);
  const half8* __restrict__ W2 = (const half8*)(wh + (size_t)(q + 2 * HG) * HG);
  float acc[3][8] = {};
  for (int i = 0; i < 16; ++i) {
    int kq = i * 32 + ks;             // half8 unit 0..499
    if (kq < 500) {
      half8 w0 = W0[kq], w1 = W1[kq], w2 = W2[kq];
#pragma unroll
      for (int kk = 0; kk < 8; ++kk) {
        half8 h8 = sH[(kq * 8 + kk) ^ (kq & 7)];   // = swz(u), u>>3 == kq
        float f0 = (float)w0[kk], f1 = (float)w1[kk], f2 = (float)w2[kk];
#pragma unroll
        for (int m = 0; m < 8; ++m) {
          float hm = (float)h8[m];
          acc[0][m] += hm * f0;
          acc[1][m] += hm * f1;
          acc[2][m] += hm * f2;
        }
      }
    }
  }
#pragma unroll
  for (int g = 0; g < 3; ++g)
#pragma unroll
    for (int m = 0; m < 8; ++m) {
      float v = acc[g][m];
      v += __shfl_down(v, 16, 32);
      v += __shfl_down(v, 8, 32);
      v += __shfl_down(v, 4, 32);
      v += __shfl_down(v, 2, 32);
      v += __shfl_down(v, 1, 32);
      if (ks == 0) sAcc[q_l][g][m] = v;
    }
  __syncthreads();
  if (tid < 64) {                     // 8 q x 8 m
    int ql2 = tid >> 3, m = tid & 7;
    int qq = blockIdx.x * 8 + ql2;
    int mg = t * BB + m;
    const float* g0 = gip + (size_t)mg * G3;
    const float* g1 = gip + (size_t)MM * G3 + (size_t)mg * G3;
    float ir  = b_ih[qq]          + g0[qq]          + g1[qq];
    float iz  = b_ih[qq + HG]     + g0[qq + HG]     + g1[qq + HG];
    float in_ = b_ih[qq + 2*HG]   + g0[qq + 2*HG]   + g1[qq + 2*HG];
    float hr  = b_hh[qq]          + sAcc[ql2][0][m];
    float hz  = b_hh[qq + HG]     + sAcc[ql2][1][m];
    float hn  = b_hh[qq + 2*HG]   + sAcc[ql2][2][m];
    float r = 1.f / (1.f + __expf(-(ir + hr)));
    float z = 1.f / (1.f + __expf(-(iz + hz)));
    float nn = tanhf(in_ + r * hn);
    float ho = ht[qq * BB + m];
    float h = (1.f - z) * nn + z * ho;
    ht_new[qq * BB + m] = h;
    if (hout) hout[m * HG + qq] = h;
  }
}

// ---------------------------------------------------------------- launcher
extern "C" void kernel_launch(void* const* d_in, const int* in_sizes, int n_in,
                              void* d_out, int out_size, void* d_ws, size_t ws_size,
                              hipStream_t stream) {
  const float* x_in = (const float*)d_in[0];
  const int*   src  = (const int*)d_in[1];
  const int*   dst  = (const int*)d_in[2];
  const float* W1   = (const float*)d_in[3];
  const float* b1   = (const float*)d_in[4];
  const float* W2   = (const float*)d_in[5];
  const float* b2   = (const float*)d_in[6];
  const float* W3   = (const float*)d_in[7];
  const float* b3   = (const float*)d_in[8];
  const float* Wih  = (const float*)d_in[9];
  const float* Whh  = (const float*)d_in[10];
  const float* bih  = (const float*)d_in[11];
  const float* bhh  = (const float*)d_in[12];
  float* out = (float*)d_out;

  float* W = (float*)d_ws;
  size_t off = 0;
  float* n_out = W + off; off += 512;
  float* n_in_ = W + off; off += 512;
  float* x0    = W + off; off += (size_t)TT * NN * BB * FIN;   // 384000
  float* xa    = W + off; off += (size_t)TT * NN * BB * HH;    // 768000
  float* xb    = W + off; off += (size_t)TT * NN * BB * HH;    // 768000
  _Float16* xseq = (_Float16*)(W + off); off += (size_t)MM * IG / 2;
  float* gip   = W + off; off += (size_t)2 * MM * G3;          // 2304000
  float* ht0   = W + off; off += (size_t)HG * BB;
  float* ht1   = W + off; off += (size_t)HG * BB;
  int* row_ptr  = (int*)(W + off); off += 512;
  int* edge_src = (int*)(W + off); off += 8000;
  off = (off + 3) & ~(size_t)3;                                // 16B align
  _Float16* whh_h = (_Float16*)(W + off); off += (size_t)G3 * HG / 2;  // 96 MB
  (void)ws_size; (void)in_sizes; (void)n_in; (void)out_size;

  k_cvt_whh<<<((size_t)G3 * HG / 8 + 255) / 256, 256, 0, stream>>>(Whh, whh_h);
  k_prep<<<1, 512, 0, stream>>>(src, dst, n_out, n_in_, row_ptr, edge_src);
  k_transpose<<<(TT * NN * BB * FIN + 255) / 256, 256, 0, stream>>>(x_in, x0);
  k_gcn<FIN, HH, true, float, false><<<TT * NN, 128, 0, stream>>>(x0, W1, b1, n_out, n_in_, row_ptr, edge_src, xa);
  k_gcn<HH, HH, true, float, false><<<TT * NN, 128, 0, stream>>>(xa, W2, b2, n_out, n_in_, row_ptr, edge_src, xb);
  k_gcn<HH, HH, false, _Float16, true><<<TT * NN, 128, 0, stream>>>(xb, W3, b3, n_out, n_in_, row_ptr, edge_src, xseq);
  k_gemm_gi_mfma<<<dim3(375, 2), 256, 0, stream>>>(xseq, Wih, gip);

  // t = 0: h_old = 0 -> gh = 0, skip the W_hh stream entirely
  k_gates0<<<BB * HG / 256, 256, 0, stream>>>(gip, bih, bhh, ht0);

  float* hcur = ht0;
  float* hnxt = ht1;
  for (int t = 1; t < TT; ++t) {
    k_ghf<<<500, 256, 0, stream>>>(hcur, whh_h, gip, bih, bhh, hnxt,
                                   (t == TT - 1) ? out : nullptr, t);
    float* tmp = hcur; hcur = hnxt; hnxt = tmp;
  }
}

// Round 9
// 526.589 us; speedup vs baseline: 2.3609x; 1.0163x over previous
//
#include <hip/hip_runtime.h>

#define NN 500
#define BB 8
#define FIN 8
#define TT 12
#define HH 16
#define EE 8000
#define HG 4000          // N*HID
#define IG 8000          // N*H3
#define G3 12000         // 3*HG
#define MM 96            // T*B

typedef __attribute__((ext_vector_type(8))) _Float16 half8;
typedef __attribute__((ext_vector_type(4))) _Float16 half4v;
typedef __attribute__((ext_vector_type(4))) float f32x4;

// ---------------------------------------------------------------- graph prep
__global__ __launch_bounds__(512) void k_prep(const int* __restrict__ src,
                                              const int* __restrict__ dst,
                                              float* __restrict__ n_out,
                                              float* __restrict__ n_in,
                                              int* __restrict__ row_ptr,
                                              int* __restrict__ edge_src) {
  __shared__ int s_dout[NN];
  __shared__ int s_din[NN];
  __shared__ int s_off[NN + 1];
  int tid = threadIdx.x;
  for (int i = tid; i < NN; i += 512) { s_dout[i] = 0; s_din[i] = 0; }
  __syncthreads();
  for (int e = tid; e < EE; e += 512) {
    atomicAdd(&s_dout[src[e]], 1);
    atomicAdd(&s_din[dst[e]], 1);
  }
  __syncthreads();
  if (tid == 0) {
    int acc = 0;
    for (int n = 0; n < NN; ++n) { s_off[n] = acc; acc += s_din[n]; }
    s_off[NN] = acc;
  }
  __syncthreads();
  for (int i = tid; i < NN; i += 512) {
    int dv = s_dout[i]; if (dv < 1) dv = 1;
    int iv = s_din[i];  if (iv < 1) iv = 1;
    n_out[i] = rsqrtf((float)dv);
    n_in[i]  = rsqrtf((float)iv);
    row_ptr[i] = s_off[i];
  }
  if (tid == 0) row_ptr[NN] = s_off[NN];
  __syncthreads();
  for (int e = tid; e < EE; e += 512) {
    int d = dst[e];
    int pos = atomicAdd(&s_off[d], 1);
    edge_src[pos] = src[e];
  }
}

// ------------------------------------------------- transpose inputs to [t][n][b][f]
__global__ __launch_bounds__(256) void k_transpose(const float* __restrict__ in,
                                                   float* __restrict__ out) {
  int idx = blockIdx.x * 256 + threadIdx.x;   // over T*N*B*FIN
  if (idx >= TT * NN * BB * FIN) return;
  int f = idx % FIN;
  int b = (idx / FIN) % BB;
  int n = (idx / (FIN * BB)) % NN;
  int t = idx / (FIN * BB * NN);
  out[idx] = in[((n * BB + b) * FIN + f) * TT + t];
}

// ---------------------------------------------------------------- GCN layer
template <int FI, int FO, bool RELU, typename OT, bool OUT_SEQ>
__global__ __launch_bounds__(128) void k_gcn(const float* __restrict__ x,
                                             const float* __restrict__ W,
                                             const float* __restrict__ bias,
                                             const float* __restrict__ n_out,
                                             const float* __restrict__ n_in,
                                             const int* __restrict__ row_ptr,
                                             const int* __restrict__ edge_src,
                                             OT* __restrict__ y) {
  int bid = blockIdx.x;             // t*NN + n
  int t = bid / NN, n = bid % NN;
  __shared__ float sW[FI * FO];
  __shared__ float sB[FO];
  __shared__ float sAgg[BB * FI];
  int tid = threadIdx.x;
  for (int i = tid; i < FI * FO; i += 128) sW[i] = W[i];
  if (tid < FO) sB[tid] = bias[tid];
  int r0 = row_ptr[n], r1 = row_ptr[n + 1];
  if (tid < BB * FI) {
    int b = tid / FI, fi = tid % FI;
    float acc = 0.f;
    for (int p = r0; p < r1; ++p) {
      int s = edge_src[p];
      acc += x[((t * NN + s) * BB + b) * FI + fi] * n_out[s];
    }
    sAgg[tid] = acc * n_in[n];
  }
  __syncthreads();
  if (tid < BB * FO) {
    int b = tid / FO, fo = tid % FO;
    float v = sB[fo];
#pragma unroll
    for (int fi = 0; fi < FI; ++fi) v += sAgg[b * FI + fi] * sW[fi * FO + fo];
    if (RELU) v = fmaxf(v, 0.f);
    int oidx = OUT_SEQ ? (((t * BB + b) * NN + n) * FO + fo)
                       : (((t * NN + n) * BB + b) * FO + fo);
    y[oidx] = (OT)v;
  }
}

// ------------------------------------------------------------ gi = X @ Wih^T
// fp16 MFMA single pass.  Xh: [96][8000] fp16, Wih: [12000][8000] fp32 (cvt in-kernel).
// gip: [2][96][12000] K-split partials.  grid (375, 2), block 256 (4 waves).
__global__ __launch_bounds__(256, 3) void k_gemm_gi_mfma(const _Float16* __restrict__ Xh,
                                                         const float* __restrict__ Wih,
                                                         float* __restrict__ gip) {
  __shared__ _Float16 sXh[96 * 40];   // rows padded to 40 halves (80B stride)
  __shared__ _Float16 sWh[32 * 40];
  int tid = threadIdx.x;
  int wave = tid >> 6, lane = tid & 63;
  int jb = blockIdx.x * 32;
  int kbase = blockIdx.y * 4000;       // K_s = 4000, 125 chunks of 32

  int xrow[3], xc4[3];
  const ushort4* px[3];
#pragma unroll
  for (int i = 0; i < 3; ++i) {
    int idx = i * 256 + tid;           // 768 units = 96 rows x 8 half4
    xrow[i] = idx >> 3; xc4[i] = idx & 7;
    px[i] = (const ushort4*)(Xh + (size_t)xrow[i] * IG + kbase + xc4[i] * 4);
  }
  int wrow = tid >> 3, wc4 = tid & 7;  // 256 f4 = 32 rows x 8 f4
  const float4* pw = (const float4*)(Wih + (size_t)(jb + wrow) * IG + kbase + wc4 * 4);

  int jt = wave & 1;                    // j-tile within block
  int mh = wave >> 1;                   // m-half (48 rows)
  f32x4 acc[3] = {{0.f,0.f,0.f,0.f},{0.f,0.f,0.f,0.f},{0.f,0.f,0.f,0.f}};

  ushort4 xr[3]; float4 wr;
#pragma unroll
  for (int i = 0; i < 3; ++i) xr[i] = px[i][0];
  wr = pw[0];

  int l15 = lane & 15;
  int colh = (lane >> 4) * 8;

  for (int c = 0; c < 125; ++c) {
    __syncthreads();
#pragma unroll
    for (int i = 0; i < 3; ++i)
      *(ushort4*)&sXh[xrow[i] * 40 + xc4[i] * 4] = xr[i];
    {
      half4v h;
      h[0] = (_Float16)wr.x; h[1] = (_Float16)wr.y;
      h[2] = (_Float16)wr.z; h[3] = (_Float16)wr.w;
      *(half4v*)&sWh[wrow * 40 + wc4 * 4] = h;
    }
    __syncthreads();
    if (c < 124) {
#pragma unroll
      for (int i = 0; i < 3; ++i) xr[i] = px[i][(c + 1) * 8];
      wr = pw[(c + 1) * 8];
    }
    half8 bfrag = *(const half8*)&sWh[(jt * 16 + l15) * 40 + colh];
#pragma unroll
    for (int t = 0; t < 3; ++t) {
      half8 afrag = *(const half8*)&sXh[(mh * 48 + t * 16 + l15) * 40 + colh];
      acc[t] = __builtin_amdgcn_mfma_f32_16x16x32_f16(afrag, bfrag, acc[t], 0, 0, 0);
    }
  }

  // D: col = lane&15 (j), row m = (lane>>4)*4 + reg  [validated rounds 3-8]
  float* out = gip + (size_t)blockIdx.y * (MM * G3);
  int j = jb + jt * 16 + l15;
#pragma unroll
  for (int t = 0; t < 3; ++t) {
    int mb = mh * 48 + t * 16 + (lane >> 4) * 4;
#pragma unroll
    for (int r = 0; r < 4; ++r)
      out[(size_t)(mb + r) * G3 + j] = acc[t][r];
  }
}

// ------------------------------------------------- GRU step 0 (h=0 -> gh=0)
__global__ __launch_bounds__(256) void k_gates0(const float* __restrict__ gip,
                                                const float* __restrict__ b_ih,
                                                const float* __restrict__ b_hh,
                                                float* __restrict__ h32n) {
  int idx = blockIdx.x * 256 + threadIdx.x;   // 32000 exact (125 blocks)
  int q = idx >> 3, m = idx & 7;
  const float* g0 = gip + (size_t)m * G3;                     // t=0: mg = m
  const float* g1 = gip + (size_t)MM * G3 + (size_t)m * G3;
  float ir  = b_ih[q]          + g0[q]          + g1[q];
  float iz  = b_ih[q + HG]     + g0[q + HG]     + g1[q + HG];
  float in_ = b_ih[q + 2*HG]   + g0[q + 2*HG]   + g1[q + 2*HG];
  float r = 1.f / (1.f + __expf(-(ir + b_hh[q])));
  float z = 1.f / (1.f + __expf(-(iz + b_hh[q + HG])));
  float nn = tanhf(in_ + r * b_hh[q + 2*HG]);
  h32n[idx] = (1.f - z) * nn;                 // h_old = 0
}

// ------------------------------------------------------------ gh = h @ Whh^T
// ht: [4000][8] fp32 k-major, Whh_h: [12000][4000] fp16, ghp: [4][8][12000].
// grid (125, 4), block 256.  96 j per block (3 rows/thread), 1000 k per slice.
__device__ __forceinline__ int swz2(int f) { return f ^ (((f >> 4) & 7) << 1); }

__global__ __launch_bounds__(256) void k_gemm_gh(const float* __restrict__ ht,
                                                 const _Float16* __restrict__ Whh_h,
                                                 float* __restrict__ ghp) {
  int j0 = blockIdx.x * 96;
  int ks = blockIdx.y;             // 0..3
  int kbase = ks * 1000;           // halves
  __shared__ float4 sH4[2000];     // [1000 k][8 m] as float4 pairs, swizzled
  int tid = threadIdx.x;
  const float4* H4 = (const float4*)ht;
#pragma unroll
  for (int l = 0; l < 8; ++l) {
    int f = l * 256 + tid;
    if (f < 2000) sH4[swz2(f)] = H4[kbase * 2 + f];
  }
  __syncthreads();
  int jl = tid >> 3;               // 0..31
  int k8 = tid & 7;                // 0..7
  const half8* W0 = (const half8*)(Whh_h + (size_t)(j0 + jl)      * HG + kbase);
  const half8* W1 = (const half8*)(Whh_h + (size_t)(j0 + jl + 32) * HG + kbase);
  const half8* W2 = (const half8*)(Whh_h + (size_t)(j0 + jl + 64) * HG + kbase);
  float acc[3][8] = {};
  for (int i = 0; i < 16; ++i) {
    int kq = i * 8 + k8;           // half8 index within slice, 0..124
    if (kq < 125) {
      half8 w0 = W0[kq], w1 = W1[kq], w2 = W2[kq];
#pragma unroll
      for (int kk = 0; kk < 8; ++kk) {
        int f = (kq * 8 + kk) * 2;
        float4 ha = sH4[swz2(f)];
        float4 hb = sH4[swz2(f + 1)];
        float hm[8] = {ha.x, ha.y, ha.z, ha.w, hb.x, hb.y, hb.z, hb.w};
        float v0 = (float)w0[kk], v1 = (float)w1[kk], v2 = (float)w2[kk];
#pragma unroll
        for (int m = 0; m < 8; ++m) {
          acc[0][m] += hm[m] * v0;
          acc[1][m] += hm[m] * v1;
          acc[2][m] += hm[m] * v2;
        }
      }
    }
  }
#pragma unroll
  for (int r = 0; r < 3; ++r)
#pragma unroll
    for (int m = 0; m < 8; ++m) {
      float v = acc[r][m];
      v += __shfl_down(v, 4, 8);
      v += __shfl_down(v, 2, 8);
      v += __shfl_down(v, 1, 8);
      acc[r][m] = v;
    }
  if (k8 == 0) {
    float* outp = ghp + (size_t)ks * (BB * G3);
#pragma unroll
    for (int r = 0; r < 3; ++r) {
      int j = j0 + jl + r * 32;
#pragma unroll
      for (int m = 0; m < 8; ++m) outp[m * G3 + j] = acc[r][m];
    }
  }
}

// ---------------- step-1 gh fused with Whh fp32->fp16 conversion (one pass)
// Same structure as k_gemm_gh but reads fp32 W, converts, writes fp16 copy
// for steps 2..11, and computes the step-1 partials in the same pass.
__global__ __launch_bounds__(256) void k_ghcvt(const float* __restrict__ ht,
                                               const float* __restrict__ Whh,
                                               _Float16* __restrict__ whh_h,
                                               float* __restrict__ ghp) {
  int j0 = blockIdx.x * 96;
  int ks = blockIdx.y;             // 0..3
  int kbase = ks * 1000;
  __shared__ float4 sH4[2000];
  int tid = threadIdx.x;
  const float4* H4 = (const float4*)ht;
#pragma unroll
  for (int l = 0; l < 8; ++l) {
    int f = l * 256 + tid;
    if (f < 2000) sH4[swz2(f)] = H4[kbase * 2 + f];
  }
  __syncthreads();
  int jl = tid >> 3;
  int k8 = tid & 7;
  int r0 = j0 + jl, r1 = j0 + jl + 32, r2 = j0 + jl + 64;
  const float4* F0 = (const float4*)(Whh + (size_t)r0 * HG + kbase);
  const float4* F1 = (const float4*)(Whh + (size_t)r1 * HG + kbase);
  const float4* F2 = (const float4*)(Whh + (size_t)r2 * HG + kbase);
  half8* O0 = (half8*)(whh_h + (size_t)r0 * HG + kbase);
  half8* O1 = (half8*)(whh_h + (size_t)r1 * HG + kbase);
  half8* O2 = (half8*)(whh_h + (size_t)r2 * HG + kbase);
  float acc[3][8] = {};
  for (int i = 0; i < 16; ++i) {
    int kq = i * 8 + k8;           // half8 unit within slice, 0..124
    if (kq < 125) {
      float4 a0 = F0[kq * 2], b0 = F0[kq * 2 + 1];
      float4 a1 = F1[kq * 2], b1 = F1[kq * 2 + 1];
      float4 a2 = F2[kq * 2], b2 = F2[kq * 2 + 1];
      half8 w0, w1, w2;
      w0[0] = (_Float16)a0.x; w0[1] = (_Float16)a0.y; w0[2] = (_Float16)a0.z; w0[3] = (_Float16)a0.w;
      w0[4] = (_Float16)b0.x; w0[5] = (_Float16)b0.y; w0[6] = (_Float16)b0.z; w0[7] = (_Float16)b0.w;
      w1[0] = (_Float16)a1.x; w1[1] = (_Float16)a1.y; w1[2] = (_Float16)a1.z; w1[3] = (_Float16)a1.w;
      w1[4] = (_Float16)b1.x; w1[5] = (_Float16)b1.y; w1[6] = (_Float16)b1.z; w1[7] = (_Float16)b1.w;
      w2[0] = (_Float16)a2.x; w2[1] = (_Float16)a2.y; w2[2] = (_Float16)a2.z; w2[3] = (_Float16)a2.w;
      w2[4] = (_Float16)b2.x; w2[5] = (_Float16)b2.y; w2[6] = (_Float16)b2.z; w2[7] = (_Float16)b2.w;
      O0[kq] = w0; O1[kq] = w1; O2[kq] = w2;
#pragma unroll
      for (int kk = 0; kk < 8; ++kk) {
        int f = (kq * 8 + kk) * 2;
        float4 ha = sH4[swz2(f)];
        float4 hb = sH4[swz2(f + 1)];
        float hm[8] = {ha.x, ha.y, ha.z, ha.w, hb.x, hb.y, hb.z, hb.w};
        float v0 = (float)w0[kk], v1 = (float)w1[kk], v2 = (float)w2[kk];
#pragma unroll
        for (int m = 0; m < 8; ++m) {
          acc[0][m] += hm[m] * v0;
          acc[1][m] += hm[m] * v1;
          acc[2][m] += hm[m] * v2;
        }
      }
    }
  }
#pragma unroll
  for (int r = 0; r < 3; ++r)
#pragma unroll
    for (int m = 0; m < 8; ++m) {
      float v = acc[r][m];
      v += __shfl_down(v, 4, 8);
      v += __shfl_down(v, 2, 8);
      v += __shfl_down(v, 1, 8);
      acc[r][m] = v;
    }
  if (k8 == 0) {
    float* outp = ghp + (size_t)ks * (BB * G3);
#pragma unroll
    for (int r = 0; r < 3; ++r) {
      int j = j0 + jl + r * 32;
#pragma unroll
      for (int m = 0; m < 8; ++m) outp[m * G3 + j] = acc[r][m];
    }
  }
}

// ---------------------------------------------------------------- gates
__global__ __launch_bounds__(256) void k_gates(const float* __restrict__ gip,
                                               const float* __restrict__ ghp,
                                               const float* __restrict__ b_ih,
                                               const float* __restrict__ b_hh,
                                               const float* __restrict__ ht_old,
                                               float* __restrict__ ht_new,
                                               float* __restrict__ hout, int t) {
  int idx = blockIdx.x * 256 + threadIdx.x;
  if (idx >= BB * HG) return;
  int b = idx / HG, q = idx % HG;
  int m = t * BB + b;
  const float* g0 = gip;
  const float* g1 = gip + (size_t)MM * G3;
  float ir = b_ih[q]          + g0[m * G3 + q]          + g1[m * G3 + q];
  float iz = b_ih[q + HG]     + g0[m * G3 + q + HG]     + g1[m * G3 + q + HG];
  float in_ = b_ih[q + 2*HG]  + g0[m * G3 + q + 2*HG]   + g1[m * G3 + q + 2*HG];
  float hr = b_hh[q], hz = b_hh[q + HG], hn = b_hh[q + 2*HG];
#pragma unroll
  for (int s = 0; s < 4; ++s) {
    const float* gh = ghp + (size_t)s * (BB * G3) + b * G3;
    hr += gh[q]; hz += gh[q + HG]; hn += gh[q + 2*HG];
  }
  float r = 1.f / (1.f + __expf(-(ir + hr)));
  float z = 1.f / (1.f + __expf(-(iz + hz)));
  float nn = tanhf(in_ + r * hn);
  float ho = ht_old[q * BB + b];
  float h = (1.f - z) * nn + z * ho;
  ht_new[q * BB + b] = h;
  if (hout) hout[b * HG + q] = h;
}

// ---------------------------------------------------------------- launcher
extern "C" void kernel_launch(void* const* d_in, const int* in_sizes, int n_in,
                              void* d_out, int out_size, void* d_ws, size_t ws_size,
                              hipStream_t stream) {
  const float* x_in = (const float*)d_in[0];
  const int*   src  = (const int*)d_in[1];
  const int*   dst  = (const int*)d_in[2];
  const float* W1   = (const float*)d_in[3];
  const float* b1   = (const float*)d_in[4];
  const float* W2   = (const float*)d_in[5];
  const float* b2   = (const float*)d_in[6];
  const float* W3   = (const float*)d_in[7];
  const float* b3   = (const float*)d_in[8];
  const float* Wih  = (const float*)d_in[9];
  const float* Whh  = (const float*)d_in[10];
  const float* bih  = (const float*)d_in[11];
  const float* bhh  = (const float*)d_in[12];
  float* out = (float*)d_out;

  float* W = (float*)d_ws;
  size_t off = 0;
  float* n_out = W + off; off += 512;
  float* n_in_ = W + off; off += 512;
  float* x0    = W + off; off += (size_t)TT * NN * BB * FIN;   // 384000
  float* xa    = W + off; off += (size_t)TT * NN * BB * HH;    // 768000
  float* xb    = W + off; off += (size_t)TT * NN * BB * HH;    // 768000
  _Float16* xseq = (_Float16*)(W + off); off += (size_t)MM * IG / 2;
  float* gip   = W + off; off += (size_t)2 * MM * G3;          // 2304000
  float* ghp   = W + off; off += (size_t)4 * BB * G3;          // 384000
  float* ht0   = W + off; off += (size_t)HG * BB;
  float* ht1   = W + off; off += (size_t)HG * BB;
  int* row_ptr  = (int*)(W + off); off += 512;
  int* edge_src = (int*)(W + off); off += 8000;
  off = (off + 3) & ~(size_t)3;                                // 16B align
  _Float16* whh_h = (_Float16*)(W + off); off += (size_t)G3 * HG / 2;  // 96 MB
  (void)ws_size; (void)in_sizes; (void)n_in; (void)out_size;

  k_prep<<<1, 512, 0, stream>>>(src, dst, n_out, n_in_, row_ptr, edge_src);
  k_transpose<<<(TT * NN * BB * FIN + 255) / 256, 256, 0, stream>>>(x_in, x0);
  k_gcn<FIN, HH, true, float, false><<<TT * NN, 128, 0, stream>>>(x0, W1, b1, n_out, n_in_, row_ptr, edge_src, xa);
  k_gcn<HH, HH, true, float, false><<<TT * NN, 128, 0, stream>>>(xa, W2, b2, n_out, n_in_, row_ptr, edge_src, xb);
  k_gcn<HH, HH, false, _Float16, true><<<TT * NN, 128, 0, stream>>>(xb, W3, b3, n_out, n_in_, row_ptr, edge_src, xseq);
  k_gemm_gi_mfma<<<dim3(375, 2), 256, 0, stream>>>(xseq, Wih, gip);

  // t = 0: h_old = 0 -> gh = 0, skip the W_hh stream entirely
  k_gates0<<<BB * HG / 256, 256, 0, stream>>>(gip, bih, bhh, ht0);

  float* hcur = ht0;
  float* hnxt = ht1;
  // t = 1: gh fused with the one-time fp32->fp16 W_hh conversion
  k_ghcvt<<<dim3(125, 4), 256, 0, stream>>>(hcur, Whh, whh_h, ghp);
  k_gates<<<(BB * HG + 255) / 256, 256, 0, stream>>>(
      gip, ghp, bih, bhh, hcur, hnxt, nullptr, 1);
  { float* tmp = hcur; hcur = hnxt; hnxt = tmp; }

  for (int t = 2; t < TT; ++t) {
    k_gemm_gh<<<dim3(125, 4), 256, 0, stream>>>(hcur, whh_h, ghp);
    k_gates<<<(BB * HG + 255) / 256, 256, 0, stream>>>(
        gip, ghp, bih, bhh, hcur, hnxt, (t == TT - 1) ? out : nullptr, t);
    float* tmp = hcur; hcur = hnxt; hnxt = tmp;
  }
}

// Round 10
// 514.100 us; speedup vs baseline: 2.4183x; 1.0243x over previous
//
#include <hip/hip_runtime.h>

#define NN 500
#define BB 8
#define FIN 8
#define TT 12
#define HH 16
#define EE 8000
#define HG 4000          // N*HID
#define IG 8000          // N*H3
#define G3 12000         // 3*HG
#define MM 96            // T*B

typedef __attribute__((ext_vector_type(8))) _Float16 half8;
typedef __attribute__((ext_vector_type(4))) _Float16 half4v;
typedef __attribute__((ext_vector_type(4))) float f32x4;

// ---------------------------------------------------------------- graph prep
__global__ __launch_bounds__(512) void k_prep(const int* __restrict__ src,
                                              const int* __restrict__ dst,
                                              float* __restrict__ n_out,
                                              float* __restrict__ n_in,
                                              int* __restrict__ row_ptr,
                                              int* __restrict__ edge_src) {
  __shared__ int s_dout[NN];
  __shared__ int s_din[NN];
  __shared__ int s_off[NN + 1];
  int tid = threadIdx.x;
  for (int i = tid; i < NN; i += 512) { s_dout[i] = 0; s_din[i] = 0; }
  __syncthreads();
  for (int e = tid; e < EE; e += 512) {
    atomicAdd(&s_dout[src[e]], 1);
    atomicAdd(&s_din[dst[e]], 1);
  }
  __syncthreads();
  if (tid == 0) {
    int acc = 0;
    for (int n = 0; n < NN; ++n) { s_off[n] = acc; acc += s_din[n]; }
    s_off[NN] = acc;
  }
  __syncthreads();
  for (int i = tid; i < NN; i += 512) {
    int dv = s_dout[i]; if (dv < 1) dv = 1;
    int iv = s_din[i];  if (iv < 1) iv = 1;
    n_out[i] = rsqrtf((float)dv);
    n_in[i]  = rsqrtf((float)iv);
    row_ptr[i] = s_off[i];
  }
  if (tid == 0) row_ptr[NN] = s_off[NN];
  __syncthreads();
  for (int e = tid; e < EE; e += 512) {
    int d = dst[e];
    int pos = atomicAdd(&s_off[d], 1);
    edge_src[pos] = src[e];
  }
}

// ------------------------------------------------- transpose inputs to [t][n][b][f]
__global__ __launch_bounds__(256) void k_transpose(const float* __restrict__ in,
                                                   float* __restrict__ out) {
  int idx = blockIdx.x * 256 + threadIdx.x;   // over T*N*B*FIN
  if (idx >= TT * NN * BB * FIN) return;
  int f = idx % FIN;
  int b = (idx / FIN) % BB;
  int n = (idx / (FIN * BB)) % NN;
  int t = idx / (FIN * BB * NN);
  out[idx] = in[((n * BB + b) * FIN + f) * TT + t];
}

// ---------------------------------------------------------------- GCN layer
template <int FI, int FO, bool RELU, typename OT, bool OUT_SEQ>
__global__ __launch_bounds__(128) void k_gcn(const float* __restrict__ x,
                                             const float* __restrict__ W,
                                             const float* __restrict__ bias,
                                             const float* __restrict__ n_out,
                                             const float* __restrict__ n_in,
                                             const int* __restrict__ row_ptr,
                                             const int* __restrict__ edge_src,
                                             OT* __restrict__ y) {
  int bid = blockIdx.x;             // t*NN + n
  int t = bid / NN, n = bid % NN;
  __shared__ float sW[FI * FO];
  __shared__ float sB[FO];
  __shared__ float sAgg[BB * FI];
  int tid = threadIdx.x;
  for (int i = tid; i < FI * FO; i += 128) sW[i] = W[i];
  if (tid < FO) sB[tid] = bias[tid];
  int r0 = row_ptr[n], r1 = row_ptr[n + 1];
  if (tid < BB * FI) {
    int b = tid / FI, fi = tid % FI;
    float acc = 0.f;
    for (int p = r0; p < r1; ++p) {
      int s = edge_src[p];
      acc += x[((t * NN + s) * BB + b) * FI + fi] * n_out[s];
    }
    sAgg[tid] = acc * n_in[n];
  }
  __syncthreads();
  if (tid < BB * FO) {
    int b = tid / FO, fo = tid % FO;
    float v = sB[fo];
#pragma unroll
    for (int fi = 0; fi < FI; ++fi) v += sAgg[b * FI + fi] * sW[fi * FO + fo];
    if (RELU) v = fmaxf(v, 0.f);
    int oidx = OUT_SEQ ? (((t * BB + b) * NN + n) * FO + fo)
                       : (((t * NN + n) * BB + b) * FO + fo);
    y[oidx] = (OT)v;
  }
}

// ------------------------------------------------------------ gi = X @ Wih^T
// fp16 MFMA single pass.  Xh: [96][8000] fp16, Wih: [12000][8000] fp32 (cvt in-kernel).
// gip: [2][96][12000] K-split partials.  grid (375, 2), block 256 (4 waves).
__global__ __launch_bounds__(256, 3) void k_gemm_gi_mfma(const _Float16* __restrict__ Xh,
                                                         const float* __restrict__ Wih,
                                                         float* __restrict__ gip) {
  __shared__ _Float16 sXh[96 * 40];   // rows padded to 40 halves (80B stride)
  __shared__ _Float16 sWh[32 * 40];
  int tid = threadIdx.x;
  int wave = tid >> 6, lane = tid & 63;
  int jb = blockIdx.x * 32;
  int kbase = blockIdx.y * 4000;       // K_s = 4000, 125 chunks of 32

  int xrow[3], xc4[3];
  const ushort4* px[3];
#pragma unroll
  for (int i = 0; i < 3; ++i) {
    int idx = i * 256 + tid;           // 768 units = 96 rows x 8 half4
    xrow[i] = idx >> 3; xc4[i] = idx & 7;
    px[i] = (const ushort4*)(Xh + (size_t)xrow[i] * IG + kbase + xc4[i] * 4);
  }
  int wrow = tid >> 3, wc4 = tid & 7;  // 256 f4 = 32 rows x 8 f4
  const float4* pw = (const float4*)(Wih + (size_t)(jb + wrow) * IG + kbase + wc4 * 4);

  int jt = wave & 1;                    // j-tile within block
  int mh = wave >> 1;                   // m-half (48 rows)
  f32x4 acc[3] = {{0.f,0.f,0.f,0.f},{0.f,0.f,0.f,0.f},{0.f,0.f,0.f,0.f}};

  ushort4 xr[3]; float4 wr;
#pragma unroll
  for (int i = 0; i < 3; ++i) xr[i] = px[i][0];
  wr = pw[0];

  int l15 = lane & 15;
  int colh = (lane >> 4) * 8;

  for (int c = 0; c < 125; ++c) {
    __syncthreads();
#pragma unroll
    for (int i = 0; i < 3; ++i)
      *(ushort4*)&sXh[xrow[i] * 40 + xc4[i] * 4] = xr[i];
    {
      half4v h;
      h[0] = (_Float16)wr.x; h[1] = (_Float16)wr.y;
      h[2] = (_Float16)wr.z; h[3] = (_Float16)wr.w;
      *(half4v*)&sWh[wrow * 40 + wc4 * 4] = h;
    }
    __syncthreads();
    if (c < 124) {
#pragma unroll
      for (int i = 0; i < 3; ++i) xr[i] = px[i][(c + 1) * 8];
      wr = pw[(c + 1) * 8];
    }
    half8 bfrag = *(const half8*)&sWh[(jt * 16 + l15) * 40 + colh];
#pragma unroll
    for (int t = 0; t < 3; ++t) {
      half8 afrag = *(const half8*)&sXh[(mh * 48 + t * 16 + l15) * 40 + colh];
      acc[t] = __builtin_amdgcn_mfma_f32_16x16x32_f16(afrag, bfrag, acc[t], 0, 0, 0);
    }
  }

  // D: col = lane&15 (j), row m = (lane>>4)*4 + reg  [validated rounds 3-9]
  float* out = gip + (size_t)blockIdx.y * (MM * G3);
  int j = jb + jt * 16 + l15;
#pragma unroll
  for (int t = 0; t < 3; ++t) {
    int mb = mh * 48 + t * 16 + (lane >> 4) * 4;
#pragma unroll
    for (int r = 0; r < 4; ++r)
      out[(size_t)(mb + r) * G3 + j] = acc[t][r];
  }
}

// ------------------------------------------------- GRU step 0 (h=0 -> gh=0)
__global__ __launch_bounds__(256) void k_gates0(const float* __restrict__ gip,
                                                const float* __restrict__ b_ih,
                                                const float* __restrict__ b_hh,
                                                float* __restrict__ h32n) {
  int idx = blockIdx.x * 256 + threadIdx.x;   // 32000 exact (125 blocks)
  int q = idx >> 3, m = idx & 7;
  const float* g0 = gip + (size_t)m * G3;                     // t=0: mg = m
  const float* g1 = gip + (size_t)MM * G3 + (size_t)m * G3;
  float ir  = b_ih[q]          + g0[q]          + g1[q];
  float iz  = b_ih[q + HG]     + g0[q + HG]     + g1[q + HG];
  float in_ = b_ih[q + 2*HG]   + g0[q + 2*HG]   + g1[q + 2*HG];
  float r = 1.f / (1.f + __expf(-(ir + b_hh[q])));
  float z = 1.f / (1.f + __expf(-(iz + b_hh[q + HG])));
  float nn = tanhf(in_ + r * b_hh[q + 2*HG]);
  h32n[idx] = (1.f - z) * nn;                 // h_old = 0
}

// ------------------------------------------------------------ gh = h @ Whh^T
// ht: [4000][8] fp32 k-major, Whh_h: [12000][4000] fp16, ghp: [4][8][12000].
// grid (250, 4), block 256 = 16 jl x 16 k8.  48 j rows per block (3/thread),
// 1000 k per slice.  1000 blocks -> ~4 blocks/CU, 16 waves/CU (latency hiding).
// Swizzle: XOR bits[4:6] into [1:3] and bit7 into bit0 -> 2-way conflicts max.
__device__ __forceinline__ int swzg(int f) {
  return f ^ (((f >> 4) & 7) << 1) ^ ((f >> 7) & 1);
}

__global__ __launch_bounds__(256) void k_gemm_gh(const float* __restrict__ ht,
                                                 const _Float16* __restrict__ Whh_h,
                                                 float* __restrict__ ghp) {
  int j0 = blockIdx.x * 48;
  int ks = blockIdx.y;             // 0..3
  int kbase = ks * 1000;           // halves
  __shared__ float4 sH4[2000];     // [1000 k][8 m] as float4 pairs, swizzled
  int tid = threadIdx.x;
  const float4* H4 = (const float4*)ht;
#pragma unroll
  for (int l = 0; l < 8; ++l) {
    int f = l * 256 + tid;
    if (f < 2000) sH4[swzg(f)] = H4[kbase * 2 + f];
  }
  __syncthreads();
  int jl = tid >> 4;               // 0..15
  int k8 = tid & 15;               // 0..15
  const half8* W0 = (const half8*)(Whh_h + (size_t)(j0 + jl)      * HG + kbase);
  const half8* W1 = (const half8*)(Whh_h + (size_t)(j0 + jl + 16) * HG + kbase);
  const half8* W2 = (const half8*)(Whh_h + (size_t)(j0 + jl + 32) * HG + kbase);
  float acc[3][8] = {};
  for (int i = 0; i < 8; ++i) {
    int kq = i * 16 + k8;          // half8 index within slice, 0..127
    if (kq < 125) {
      half8 w0 = W0[kq], w1 = W1[kq], w2 = W2[kq];
#pragma unroll
      for (int kk = 0; kk < 8; ++kk) {
        int f = (kq * 8 + kk) * 2;
        float4 ha = sH4[swzg(f)];
        float4 hb = sH4[swzg(f + 1)];
        float hm[8] = {ha.x, ha.y, ha.z, ha.w, hb.x, hb.y, hb.z, hb.w};
        float v0 = (float)w0[kk], v1 = (float)w1[kk], v2 = (float)w2[kk];
#pragma unroll
        for (int m = 0; m < 8; ++m) {
          acc[0][m] += hm[m] * v0;
          acc[1][m] += hm[m] * v1;
          acc[2][m] += hm[m] * v2;
        }
      }
    }
  }
#pragma unroll
  for (int r = 0; r < 3; ++r)
#pragma unroll
    for (int m = 0; m < 8; ++m) {
      float v = acc[r][m];
      v += __shfl_down(v, 8, 16);
      v += __shfl_down(v, 4, 16);
      v += __shfl_down(v, 2, 16);
      v += __shfl_down(v, 1, 16);
      acc[r][m] = v;
    }
  if (k8 == 0) {
    float* outp = ghp + (size_t)ks * (BB * G3);
#pragma unroll
    for (int r = 0; r < 3; ++r) {
      int j = j0 + jl + r * 16;
#pragma unroll
      for (int m = 0; m < 8; ++m) outp[m * G3 + j] = acc[r][m];
    }
  }
}

// ---------------- step-1 gh fused with Whh fp32->fp16 conversion (one pass)
// Same tiling as k_gemm_gh; reads fp32 W, converts, writes fp16 copy for
// steps 2..11, computes step-1 partials in the same pass.
__global__ __launch_bounds__(256) void k_ghcvt(const float* __restrict__ ht,
                                               const float* __restrict__ Whh,
                                               _Float16* __restrict__ whh_h,
                                               float* __restrict__ ghp) {
  int j0 = blockIdx.x * 48;
  int ks = blockIdx.y;             // 0..3
  int kbase = ks * 1000;
  __shared__ float4 sH4[2000];
  int tid = threadIdx.x;
  const float4* H4 = (const float4*)ht;
#pragma unroll
  for (int l = 0; l < 8; ++l) {
    int f = l * 256 + tid;
    if (f < 2000) sH4[swzg(f)] = H4[kbase * 2 + f];
  }
  __syncthreads();
  int jl = tid >> 4;
  int k8 = tid & 15;
  int r0 = j0 + jl, r1 = j0 + jl + 16, r2 = j0 + jl + 32;
  const float4* F0 = (const float4*)(Whh + (size_t)r0 * HG + kbase);
  const float4* F1 = (const float4*)(Whh + (size_t)r1 * HG + kbase);
  const float4* F2 = (const float4*)(Whh + (size_t)r2 * HG + kbase);
  half8* O0 = (half8*)(whh_h + (size_t)r0 * HG + kbase);
  half8* O1 = (half8*)(whh_h + (size_t)r1 * HG + kbase);
  half8* O2 = (half8*)(whh_h + (size_t)r2 * HG + kbase);
  float acc[3][8] = {};
  for (int i = 0; i < 8; ++i) {
    int kq = i * 16 + k8;          // half8 unit within slice, 0..127
    if (kq < 125) {
      float4 a0 = F0[kq * 2], b0 = F0[kq * 2 + 1];
      float4 a1 = F1[kq * 2], b1 = F1[kq * 2 + 1];
      float4 a2 = F2[kq * 2], b2 = F2[kq * 2 + 1];
      half8 w0, w1, w2;
      w0[0] = (_Float16)a0.x; w0[1] = (_Float16)a0.y; w0[2] = (_Float16)a0.z; w0[3] = (_Float16)a0.w;
      w0[4] = (_Float16)b0.x; w0[5] = (_Float16)b0.y; w0[6] = (_Float16)b0.z; w0[7] = (_Float16)b0.w;
      w1[0] = (_Float16)a1.x; w1[1] = (_Float16)a1.y; w1[2] = (_Float16)a1.z; w1[3] = (_Float16)a1.w;
      w1[4] = (_Float16)b1.x; w1[5] = (_Float16)b1.y; w1[6] = (_Float16)b1.z; w1[7] = (_Float16)b1.w;
      w2[0] = (_Float16)a2.x; w2[1] = (_Float16)a2.y; w2[2] = (_Float16)a2.z; w2[3] = (_Float16)a2.w;
      w2[4] = (_Float16)b2.x; w2[5] = (_Float16)b2.y; w2[6] = (_Float16)b2.z; w2[7] = (_Float16)b2.w;
      O0[kq] = w0; O1[kq] = w1; O2[kq] = w2;
#pragma unroll
      for (int kk = 0; kk < 8; ++kk) {
        int f = (kq * 8 + kk) * 2;
        float4 ha = sH4[swzg(f)];
        float4 hb = sH4[swzg(f + 1)];
        float hm[8] = {ha.x, ha.y, ha.z, ha.w, hb.x, hb.y, hb.z, hb.w};
        float v0 = (float)w0[kk], v1 = (float)w1[kk], v2 = (float)w2[kk];
#pragma unroll
        for (int m = 0; m < 8; ++m) {
          acc[0][m] += hm[m] * v0;
          acc[1][m] += hm[m] * v1;
          acc[2][m] += hm[m] * v2;
        }
      }
    }
  }
#pragma unroll
  for (int r = 0; r < 3; ++r)
#pragma unroll
    for (int m = 0; m < 8; ++m) {
      float v = acc[r][m];
      v += __shfl_down(v, 8, 16);
      v += __shfl_down(v, 4, 16);
      v += __shfl_down(v, 2, 16);
      v += __shfl_down(v, 1, 16);
      acc[r][m] = v;
    }
  if (k8 == 0) {
    float* outp = ghp + (size_t)ks * (BB * G3);
#pragma unroll
    for (int r = 0; r < 3; ++r) {
      int j = j0 + jl + r * 16;
#pragma unroll
      for (int m = 0; m < 8; ++m) outp[m * G3 + j] = acc[r][m];
    }
  }
}

// ---------------------------------------------------------------- gates
__global__ __launch_bounds__(256) void k_gates(const float* __restrict__ gip,
                                               const float* __restrict__ ghp,
                                               const float* __restrict__ b_ih,
                                               const float* __restrict__ b_hh,
                                               const float* __restrict__ ht_old,
                                               float* __restrict__ ht_new,
                                               float* __restrict__ hout, int t) {
  int idx = blockIdx.x * 256 + threadIdx.x;
  if (idx >= BB * HG) return;
  int b = idx / HG, q = idx % HG;
  int m = t * BB + b;
  const float* g0 = gip;
  const float* g1 = gip + (size_t)MM * G3;
  float ir = b_ih[q]          + g0[m * G3 + q]          + g1[m * G3 + q];
  float iz = b_ih[q + HG]     + g0[m * G3 + q + HG]     + g1[m * G3 + q + HG];
  float in_ = b_ih[q + 2*HG]  + g0[m * G3 + q + 2*HG]   + g1[m * G3 + q + 2*HG];
  float hr = b_hh[q], hz = b_hh[q + HG], hn = b_hh[q + 2*HG];
#pragma unroll
  for (int s = 0; s < 4; ++s) {
    const float* gh = ghp + (size_t)s * (BB * G3) + b * G3;
    hr += gh[q]; hz += gh[q + HG]; hn += gh[q + 2*HG];
  }
  float r = 1.f / (1.f + __expf(-(ir + hr)));
  float z = 1.f / (1.f + __expf(-(iz + hz)));
  float nn = tanhf(in_ + r * hn);
  float ho = ht_old[q * BB + b];
  float h = (1.f - z) * nn + z * ho;
  ht_new[q * BB + b] = h;
  if (hout) hout[b * HG + q] = h;
}

// ---------------------------------------------------------------- launcher
extern "C" void kernel_launch(void* const* d_in, const int* in_sizes, int n_in,
                              void* d_out, int out_size, void* d_ws, size_t ws_size,
                              hipStream_t stream) {
  const float* x_in = (const float*)d_in[0];
  const int*   src  = (const int*)d_in[1];
  const int*   dst  = (const int*)d_in[2];
  const float* W1   = (const float*)d_in[3];
  const float* b1   = (const float*)d_in[4];
  const float* W2   = (const float*)d_in[5];
  const float* b2   = (const float*)d_in[6];
  const float* W3   = (const float*)d_in[7];
  const float* b3   = (const float*)d_in[8];
  const float* Wih  = (const float*)d_in[9];
  const float* Whh  = (const float*)d_in[10];
  const float* bih  = (const float*)d_in[11];
  const float* bhh  = (const float*)d_in[12];
  float* out = (float*)d_out;

  float* W = (float*)d_ws;
  size_t off = 0;
  float* n_out = W + off; off += 512;
  float* n_in_ = W + off; off += 512;
  float* x0    = W + off; off += (size_t)TT * NN * BB * FIN;   // 384000
  float* xa    = W + off; off += (size_t)TT * NN * BB * HH;    // 768000
  float* xb    = W + off; off += (size_t)TT * NN * BB * HH;    // 768000
  _Float16* xseq = (_Float16*)(W + off); off += (size_t)MM * IG / 2;
  float* gip   = W + off; off += (size_t)2 * MM * G3;          // 2304000
  float* ghp   = W + off; off += (size_t)4 * BB * G3;          // 384000
  float* ht0   = W + off; off += (size_t)HG * BB;
  float* ht1   = W + off; off += (size_t)HG * BB;
  int* row_ptr  = (int*)(W + off); off += 512;
  int* edge_src = (int*)(W + off); off += 8000;
  off = (off + 3) & ~(size_t)3;                                // 16B align
  _Float16* whh_h = (_Float16*)(W + off); off += (size_t)G3 * HG / 2 + 64;  // 96 MB
  (void)ws_size; (void)in_sizes; (void)n_in; (void)out_size;

  k_prep<<<1, 512, 0, stream>>>(src, dst, n_out, n_in_, row_ptr, edge_src);
  k_transpose<<<(TT * NN * BB * FIN + 255) / 256, 256, 0, stream>>>(x_in, x0);
  k_gcn<FIN, HH, true, float, false><<<TT * NN, 128, 0, stream>>>(x0, W1, b1, n_out, n_in_, row_ptr, edge_src, xa);
  k_gcn<HH, HH, true, float, false><<<TT * NN, 128, 0, stream>>>(xa, W2, b2, n_out, n_in_, row_ptr, edge_src, xb);
  k_gcn<HH, HH, false, _Float16, true><<<TT * NN, 128, 0, stream>>>(xb, W3, b3, n_out, n_in_, row_ptr, edge_src, xseq);
  k_gemm_gi_mfma<<<dim3(375, 2), 256, 0, stream>>>(xseq, Wih, gip);

  // t = 0: h_old = 0 -> gh = 0, skip the W_hh stream entirely
  k_gates0<<<BB * HG / 256, 256, 0, stream>>>(gip, bih, bhh, ht0);

  float* hcur = ht0;
  float* hnxt = ht1;
  // t = 1: gh fused with the one-time fp32->fp16 W_hh conversion
  k_ghcvt<<<dim3(250, 4), 256, 0, stream>>>(hcur, Whh, whh_h, ghp);
  k_gates<<<(BB * HG + 255) / 256, 256, 0, stream>>>(
      gip, ghp, bih, bhh, hcur, hnxt, nullptr, 1);
  { float* tmp = hcur; hcur = hnxt; hnxt = tmp; }

  for (int t = 2; t < TT; ++t) {
    k_gemm_gh<<<dim3(250, 4), 256, 0, stream>>>(hcur, whh_h, ghp);
    k_gates<<<(BB * HG + 255) / 256, 256, 0, stream>>>(
        gip, ghp, bih, bhh, hcur, hnxt, (t == TT - 1) ? out : nullptr, t);
    float* tmp = hcur; hcur = hnxt; hnxt = tmp;
  }
}

// Round 11
// 471.086 us; speedup vs baseline: 2.6391x; 1.0913x over previous
//
#include <hip/hip_runtime.h>

#define NN 500
#define BB 8
#define FIN 8
#define TT 12
#define HH 16
#define EE 8000
#define HG 4000          // N*HID
#define IG 8000          // N*H3
#define G3 12000         // 3*HG
#define MM 96            // T*B

typedef __attribute__((ext_vector_type(8))) _Float16 half8;
typedef __attribute__((ext_vector_type(4))) _Float16 half4v;
typedef __attribute__((ext_vector_type(4))) float f32x4;

// ---------------------------------------------------------------- graph prep
__global__ __launch_bounds__(512) void k_prep(const int* __restrict__ src,
                                              const int* __restrict__ dst,
                                              float* __restrict__ n_out,
                                              float* __restrict__ n_in,
                                              int* __restrict__ row_ptr,
                                              int* __restrict__ edge_src) {
  __shared__ int s_dout[NN];
  __shared__ int s_din[NN];
  __shared__ int s_off[NN + 1];
  int tid = threadIdx.x;
  for (int i = tid; i < NN; i += 512) { s_dout[i] = 0; s_din[i] = 0; }
  __syncthreads();
  for (int e = tid; e < EE; e += 512) {
    atomicAdd(&s_dout[src[e]], 1);
    atomicAdd(&s_din[dst[e]], 1);
  }
  __syncthreads();
  if (tid == 0) {
    int acc = 0;
    for (int n = 0; n < NN; ++n) { s_off[n] = acc; acc += s_din[n]; }
    s_off[NN] = acc;
  }
  __syncthreads();
  for (int i = tid; i < NN; i += 512) {
    int dv = s_dout[i]; if (dv < 1) dv = 1;
    int iv = s_din[i];  if (iv < 1) iv = 1;
    n_out[i] = rsqrtf((float)dv);
    n_in[i]  = rsqrtf((float)iv);
    row_ptr[i] = s_off[i];
  }
  if (tid == 0) row_ptr[NN] = s_off[NN];
  __syncthreads();
  for (int e = tid; e < EE; e += 512) {
    int d = dst[e];
    int pos = atomicAdd(&s_off[d], 1);
    edge_src[pos] = src[e];
  }
}

// ------------------------------------------------- transpose inputs to [t][n][b][f]
__global__ __launch_bounds__(256) void k_transpose(const float* __restrict__ in,
                                                   float* __restrict__ out) {
  int idx = blockIdx.x * 256 + threadIdx.x;   // over T*N*B*FIN
  if (idx >= TT * NN * BB * FIN) return;
  int f = idx % FIN;
  int b = (idx / FIN) % BB;
  int n = (idx / (FIN * BB)) % NN;
  int t = idx / (FIN * BB * NN);
  out[idx] = in[((n * BB + b) * FIN + f) * TT + t];
}

// ---------------------------------------------------------------- GCN layer
template <int FI, int FO, bool RELU, typename OT, bool OUT_SEQ>
__global__ __launch_bounds__(128) void k_gcn(const float* __restrict__ x,
                                             const float* __restrict__ W,
                                             const float* __restrict__ bias,
                                             const float* __restrict__ n_out,
                                             const float* __restrict__ n_in,
                                             const int* __restrict__ row_ptr,
                                             const int* __restrict__ edge_src,
                                             OT* __restrict__ y) {
  int bid = blockIdx.x;             // t*NN + n
  int t = bid / NN, n = bid % NN;
  __shared__ float sW[FI * FO];
  __shared__ float sB[FO];
  __shared__ float sAgg[BB * FI];
  int tid = threadIdx.x;
  for (int i = tid; i < FI * FO; i += 128) sW[i] = W[i];
  if (tid < FO) sB[tid] = bias[tid];
  int r0 = row_ptr[n], r1 = row_ptr[n + 1];
  if (tid < BB * FI) {
    int b = tid / FI, fi = tid % FI;
    float acc = 0.f;
    for (int p = r0; p < r1; ++p) {
      int s = edge_src[p];
      acc += x[((t * NN + s) * BB + b) * FI + fi] * n_out[s];
    }
    sAgg[tid] = acc * n_in[n];
  }
  __syncthreads();
  if (tid < BB * FO) {
    int b = tid / FO, fo = tid % FO;
    float v = sB[fo];
#pragma unroll
    for (int fi = 0; fi < FI; ++fi) v += sAgg[b * FI + fi] * sW[fi * FO + fo];
    if (RELU) v = fmaxf(v, 0.f);
    int oidx = OUT_SEQ ? (((t * BB + b) * NN + n) * FO + fo)
                       : (((t * NN + n) * BB + b) * FO + fo);
    y[oidx] = (OT)v;
  }
}

// ------------------------------------------------------------ gi = X @ Wih^T
// fp16 MFMA single pass.  Xh: [96][8000] fp16, Wih: [12000][8000] fp32 (cvt in-kernel).
// gip: [2][96][12000] K-split partials.  grid (375, 2), block 256 (4 waves).
__global__ __launch_bounds__(256, 3) void k_gemm_gi_mfma(const _Float16* __restrict__ Xh,
                                                         const float* __restrict__ Wih,
                                                         float* __restrict__ gip) {
  __shared__ _Float16 sXh[96 * 40];   // rows padded to 40 halves (80B stride)
  __shared__ _Float16 sWh[32 * 40];
  int tid = threadIdx.x;
  int wave = tid >> 6, lane = tid & 63;
  int jb = blockIdx.x * 32;
  int kbase = blockIdx.y * 4000;       // K_s = 4000, 125 chunks of 32

  int xrow[3], xc4[3];
  const ushort4* px[3];
#pragma unroll
  for (int i = 0; i < 3; ++i) {
    int idx = i * 256 + tid;           // 768 units = 96 rows x 8 half4
    xrow[i] = idx >> 3; xc4[i] = idx & 7;
    px[i] = (const ushort4*)(Xh + (size_t)xrow[i] * IG + kbase + xc4[i] * 4);
  }
  int wrow = tid >> 3, wc4 = tid & 7;  // 256 f4 = 32 rows x 8 f4
  const float4* pw = (const float4*)(Wih + (size_t)(jb + wrow) * IG + kbase + wc4 * 4);

  int jt = wave & 1;                    // j-tile within block
  int mh = wave >> 1;                   // m-half (48 rows)
  f32x4 acc[3] = {{0.f,0.f,0.f,0.f},{0.f,0.f,0.f,0.f},{0.f,0.f,0.f,0.f}};

  ushort4 xr[3]; float4 wr;
#pragma unroll
  for (int i = 0; i < 3; ++i) xr[i] = px[i][0];
  wr = pw[0];

  int l15 = lane & 15;
  int colh = (lane >> 4) * 8;

  for (int c = 0; c < 125; ++c) {
    __syncthreads();
#pragma unroll
    for (int i = 0; i < 3; ++i)
      *(ushort4*)&sXh[xrow[i] * 40 + xc4[i] * 4] = xr[i];
    {
      half4v h;
      h[0] = (_Float16)wr.x; h[1] = (_Float16)wr.y;
      h[2] = (_Float16)wr.z; h[3] = (_Float16)wr.w;
      *(half4v*)&sWh[wrow * 40 + wc4 * 4] = h;
    }
    __syncthreads();
    if (c < 124) {
#pragma unroll
      for (int i = 0; i < 3; ++i) xr[i] = px[i][(c + 1) * 8];
      wr = pw[(c + 1) * 8];
    }
    half8 bfrag = *(const half8*)&sWh[(jt * 16 + l15) * 40 + colh];
#pragma unroll
    for (int t = 0; t < 3; ++t) {
      half8 afrag = *(const half8*)&sXh[(mh * 48 + t * 16 + l15) * 40 + colh];
      acc[t] = __builtin_amdgcn_mfma_f32_16x16x32_f16(afrag, bfrag, acc[t], 0, 0, 0);
    }
  }

  // D: col = lane&15 (j), row m = (lane>>4)*4 + reg  [validated rounds 3-10]
  float* out = gip + (size_t)blockIdx.y * (MM * G3);
  int j = jb + jt * 16 + l15;
#pragma unroll
  for (int t = 0; t < 3; ++t) {
    int mb = mh * 48 + t * 16 + (lane >> 4) * 4;
#pragma unroll
    for (int r = 0; r < 4; ++r)
      out[(size_t)(mb + r) * G3 + j] = acc[t][r];
  }
}

// ------------------------------------------------- GRU step 0 (h=0 -> gh=0)
__global__ __launch_bounds__(256) void k_gates0(const float* __restrict__ gip,
                                                const float* __restrict__ b_ih,
                                                const float* __restrict__ b_hh,
                                                float* __restrict__ h32n,
                                                _Float16* __restrict__ h_t) {
  int idx = blockIdx.x * 256 + threadIdx.x;   // 32000 exact (125 blocks)
  int q = idx >> 3, m = idx & 7;
  const float* g0 = gip + (size_t)m * G3;                     // t=0: mg = m
  const float* g1 = gip + (size_t)MM * G3 + (size_t)m * G3;
  float ir  = b_ih[q]          + g0[q]          + g1[q];
  float iz  = b_ih[q + HG]     + g0[q + HG]     + g1[q + HG];
  float in_ = b_ih[q + 2*HG]   + g0[q + 2*HG]   + g1[q + 2*HG];
  float r = 1.f / (1.f + __expf(-(ir + b_hh[q])));
  float z = 1.f / (1.f + __expf(-(iz + b_hh[q + HG])));
  float nn = tanhf(in_ + r * b_hh[q + 2*HG]);
  float h = (1.f - z) * nn;                   // h_old = 0
  h32n[idx] = h;
  h_t[(size_t)m * HG + q] = (_Float16)h;      // transposed fp16 for MFMA B-operand
}

// ------------------------------------------------------------ gh = Whh @ h (MFMA)
// A = 16 W-rows direct from global (16B/lane contiguous); B = h_t[8][4000] fp16
// (64 KB, L1-resident; rows 8..15 alias rows 0..7, cols 8..15 of D unused).
// D: col = lane&15 = m, row = (lane>>4)*4+r = q-local  [same mapping as gi].
// grid (188, 4): 64 j per block (4 waves x 16), k-slices {1024,1024,1024,928}.
// No LDS, no VALU FMAs: pure load+MFMA stream -> can consume L3 BW.
__global__ __launch_bounds__(256) void k_ghm(const _Float16* __restrict__ wh,
                                             const _Float16* __restrict__ h_t,
                                             float* __restrict__ ghp) {
  int tid = threadIdx.x;
  int wave = tid >> 6, lane = tid & 63;
  int ks = blockIdx.y;
  int kbase = ks * 1024;
  int kn = (ks == 3) ? 29 : 32;        // 928 = 29*32
  int l15 = lane & 15;
  int ko = (lane >> 4) * 8;
  int row = blockIdx.x * 64 + wave * 16 + l15;
  int rowc = row < G3 ? row : G3 - 1;  // clamp tail (store masked below)
  const half8* __restrict__ A  = (const half8*)(wh + (size_t)rowc * HG + kbase + ko);
  const half8* __restrict__ Bp = (const half8*)(h_t + (size_t)(l15 & 7) * HG + kbase + ko);
  f32x4 acc = {0.f, 0.f, 0.f, 0.f};
#pragma unroll 4
  for (int i = 0; i < kn; ++i)
    acc = __builtin_amdgcn_mfma_f32_16x16x32_f16(A[i * 4], Bp[i * 4], acc, 0, 0, 0);
  if (l15 < 8) {
    float* outp = ghp + (size_t)ks * (BB * G3) + (size_t)l15 * G3;
    int jb = blockIdx.x * 64 + wave * 16 + (lane >> 4) * 4;
#pragma unroll
    for (int r = 0; r < 4; ++r) {
      int j = jb + r;
      if (j < G3) outp[j] = acc[r];
    }
  }
}

// ---------------- step-1 variant: reads fp32 Whh, converts, writes fp16 copy
__global__ __launch_bounds__(256) void k_ghcvtm(const float* __restrict__ Whh,
                                                _Float16* __restrict__ whh_h,
                                                const _Float16* __restrict__ h_t,
                                                float* __restrict__ ghp) {
  int tid = threadIdx.x;
  int wave = tid >> 6, lane = tid & 63;
  int ks = blockIdx.y;
  int kbase = ks * 1024;
  int kn = (ks == 3) ? 29 : 32;
  int l15 = lane & 15;
  int ko = (lane >> 4) * 8;
  int row = blockIdx.x * 64 + wave * 16 + l15;
  int rowc = row < G3 ? row : G3 - 1;
  const float4* __restrict__ F = (const float4*)(Whh + (size_t)rowc * HG + kbase + ko);
  half8* __restrict__ O = (half8*)(whh_h + (size_t)rowc * HG + kbase + ko);
  const half8* __restrict__ Bp = (const half8*)(h_t + (size_t)(l15 & 7) * HG + kbase + ko);
  f32x4 acc = {0.f, 0.f, 0.f, 0.f};
#pragma unroll 2
  for (int i = 0; i < kn; ++i) {
    float4 x = F[i * 8], y = F[i * 8 + 1];
    half8 a;
    a[0] = (_Float16)x.x; a[1] = (_Float16)x.y; a[2] = (_Float16)x.z; a[3] = (_Float16)x.w;
    a[4] = (_Float16)y.x; a[5] = (_Float16)y.y; a[6] = (_Float16)y.z; a[7] = (_Float16)y.w;
    O[i * 4] = a;                      // clamped tail rows rewrite same bytes: benign
    acc = __builtin_amdgcn_mfma_f32_16x16x32_f16(a, Bp[i * 4], acc, 0, 0, 0);
  }
  if (l15 < 8) {
    float* outp = ghp + (size_t)ks * (BB * G3) + (size_t)l15 * G3;
    int jb = blockIdx.x * 64 + wave * 16 + (lane >> 4) * 4;
#pragma unroll
    for (int r = 0; r < 4; ++r) {
      int j = jb + r;
      if (j < G3) outp[j] = acc[r];
    }
  }
}

// ---------------------------------------------------------------- gates
__global__ __launch_bounds__(256) void k_gates(const float* __restrict__ gip,
                                               const float* __restrict__ ghp,
                                               const float* __restrict__ b_ih,
                                               const float* __restrict__ b_hh,
                                               const float* __restrict__ ht_old,
                                               float* __restrict__ ht_new,
                                               _Float16* __restrict__ h_t,
                                               float* __restrict__ hout, int t) {
  int idx = blockIdx.x * 256 + threadIdx.x;
  if (idx >= BB * HG) return;
  int b = idx / HG, q = idx % HG;
  int m = t * BB + b;
  const float* g0 = gip;
  const float* g1 = gip + (size_t)MM * G3;
  float ir = b_ih[q]          + g0[m * G3 + q]          + g1[m * G3 + q];
  float iz = b_ih[q + HG]     + g0[m * G3 + q + HG]     + g1[m * G3 + q + HG];
  float in_ = b_ih[q + 2*HG]  + g0[m * G3 + q + 2*HG]   + g1[m * G3 + q + 2*HG];
  float hr = b_hh[q], hz = b_hh[q + HG], hn = b_hh[q + 2*HG];
#pragma unroll
  for (int s = 0; s < 4; ++s) {
    const float* gh = ghp + (size_t)s * (BB * G3) + b * G3;
    hr += gh[q]; hz += gh[q + HG]; hn += gh[q + 2*HG];
  }
  float r = 1.f / (1.f + __expf(-(ir + hr)));
  float z = 1.f / (1.f + __expf(-(iz + hz)));
  float nn = tanhf(in_ + r * hn);
  float ho = ht_old[q * BB + b];
  float h = (1.f - z) * nn + z * ho;
  ht_new[q * BB + b] = h;
  h_t[(size_t)b * HG + q] = (_Float16)h;
  if (hout) hout[b * HG + q] = h;
}

// ---------------------------------------------------------------- launcher
extern "C" void kernel_launch(void* const* d_in, const int* in_sizes, int n_in,
                              void* d_out, int out_size, void* d_ws, size_t ws_size,
                              hipStream_t stream) {
  const float* x_in = (const float*)d_in[0];
  const int*   src  = (const int*)d_in[1];
  const int*   dst  = (const int*)d_in[2];
  const float* W1   = (const float*)d_in[3];
  const float* b1   = (const float*)d_in[4];
  const float* W2   = (const float*)d_in[5];
  const float* b2   = (const float*)d_in[6];
  const float* W3   = (const float*)d_in[7];
  const float* b3   = (const float*)d_in[8];
  const float* Wih  = (const float*)d_in[9];
  const float* Whh  = (const float*)d_in[10];
  const float* bih  = (const float*)d_in[11];
  const float* bhh  = (const float*)d_in[12];
  float* out = (float*)d_out;

  float* W = (float*)d_ws;
  size_t off = 0;
  float* n_out = W + off; off += 512;
  float* n_in_ = W + off; off += 512;
  float* x0    = W + off; off += (size_t)TT * NN * BB * FIN;   // 384000
  float* xa    = W + off; off += (size_t)TT * NN * BB * HH;    // 768000
  float* xb    = W + off; off += (size_t)TT * NN * BB * HH;    // 768000
  _Float16* xseq = (_Float16*)(W + off); off += (size_t)MM * IG / 2;
  float* gip   = W + off; off += (size_t)2 * MM * G3;          // 2304000
  float* ghp   = W + off; off += (size_t)4 * BB * G3;          // 384000
  float* ht0   = W + off; off += (size_t)HG * BB;
  float* ht1   = W + off; off += (size_t)HG * BB;
  _Float16* h_t = (_Float16*)(W + off); off += (size_t)HG * BB / 2;  // [8][4000] fp16
  int* row_ptr  = (int*)(W + off); off += 512;
  int* edge_src = (int*)(W + off); off += 8000;
  off = (off + 3) & ~(size_t)3;                                // 16B align
  _Float16* whh_h = (_Float16*)(W + off); off += (size_t)G3 * HG / 2 + 64;  // 96 MB
  (void)ws_size; (void)in_sizes; (void)n_in; (void)out_size;

  k_prep<<<1, 512, 0, stream>>>(src, dst, n_out, n_in_, row_ptr, edge_src);
  k_transpose<<<(TT * NN * BB * FIN + 255) / 256, 256, 0, stream>>>(x_in, x0);
  k_gcn<FIN, HH, true, float, false><<<TT * NN, 128, 0, stream>>>(x0, W1, b1, n_out, n_in_, row_ptr, edge_src, xa);
  k_gcn<HH, HH, true, float, false><<<TT * NN, 128, 0, stream>>>(xa, W2, b2, n_out, n_in_, row_ptr, edge_src, xb);
  k_gcn<HH, HH, false, _Float16, true><<<TT * NN, 128, 0, stream>>>(xb, W3, b3, n_out, n_in_, row_ptr, edge_src, xseq);
  k_gemm_gi_mfma<<<dim3(375, 2), 256, 0, stream>>>(xseq, Wih, gip);

  // t = 0: h_old = 0 -> gh = 0, skip the W_hh stream entirely
  k_gates0<<<BB * HG / 256, 256, 0, stream>>>(gip, bih, bhh, ht0, h_t);

  float* hcur = ht0;
  float* hnxt = ht1;
  // t = 1: gh fused with the one-time fp32->fp16 W_hh conversion
  k_ghcvtm<<<dim3(188, 4), 256, 0, stream>>>(Whh, whh_h, h_t, ghp);
  k_gates<<<(BB * HG + 255) / 256, 256, 0, stream>>>(
      gip, ghp, bih, bhh, hcur, hnxt, h_t, nullptr, 1);
  { float* tmp = hcur; hcur = hnxt; hnxt = tmp; }

  for (int t = 2; t < TT; ++t) {
    k_ghm<<<dim3(188, 4), 256, 0, stream>>>(whh_h, h_t, ghp);
    k_gates<<<(BB * HG + 255) / 256, 256, 0, stream>>>(
        gip, ghp, bih, bhh, hcur, hnxt, h_t, (t == TT - 1) ? out : nullptr, t);
    float* tmp = hcur; hcur = hnxt; hnxt = tmp;
  }
}